// Round 4
// baseline (1096.669 us; speedup 1.0000x reference)
//
#include <hip/hip_runtime.h>

#define B_ 2
#define N_ 16384
#define M_ 4096
#define D_ 128
#define NSPLIT 4

typedef __attribute__((ext_vector_type(8))) short s8;     // 8 bf16 (4 VGPRs)
typedef __attribute__((ext_vector_type(4))) float f4;     // MFMA C/D + float4 loads
typedef __attribute__((ext_vector_type(4))) unsigned short us4;
typedef unsigned short u16;

__device__ __forceinline__ u16 f2b(float f) {   // RNE float->bf16
  unsigned int x = __float_as_uint(f);
  unsigned int r = x + 0x7fffu + ((x >> 16) & 1u);
  return (u16)(r >> 16);
}
__device__ __forceinline__ s8 ld8(const u16* p) {
  return *reinterpret_cast<const s8*>(p);
}
// Load 8 consecutive f32 (32B, 16B-aligned) and convert to 8 bf16 lanes.
__device__ __forceinline__ s8 ldcvt8(const float* p) {
  f4 x = *reinterpret_cast<const f4*>(p);
  f4 y = *reinterpret_cast<const f4*>(p + 4);
  s8 r;
  r[0] = (short)f2b(x[0]); r[1] = (short)f2b(x[1]);
  r[2] = (short)f2b(x[2]); r[3] = (short)f2b(x[3]);
  r[4] = (short)f2b(y[0]); r[5] = (short)f2b(y[1]);
  r[6] = (short)f2b(y[2]); r[7] = (short)f2b(y[3]);
  return r;
}
__device__ __forceinline__ f4 mfma16(s8 a, s8 b, f4 c) {
  return __builtin_amdgcn_mfma_f32_16x16x32_bf16(a, b, c, 0, 0, 0);
}
__device__ __forceinline__ float clamp50(float x) {
  return fminf(fmaxf(x, -50.f), 50.f);
}

// Transpose seven 128x128 f32 weight matrices into ws as bf16 Wt[n][k] (B-frags).
__global__ void wtrans(const float* a0, const float* a1, const float* a2, const float* a3,
                       const float* a4, const float* a5, const float* a6, u16* dst) {
  const float* s;
  switch (blockIdx.x) {
    case 0: s = a0; break; case 1: s = a1; break; case 2: s = a2; break;
    case 3: s = a3; break; case 4: s = a4; break; case 5: s = a5; break;
    default: s = a6; break;
  }
  u16* d = dst + blockIdx.x * 16384;
  for (int i = threadIdx.x; i < 16384; i += 256) {
    int r = i >> 7, c = i & 127;
    d[c * 128 + r] = f2b(s[i]);
  }
}

// Fused 2-layer MLP: out = relu(X@W1+b1)@W2+b2 (X f32, out bf16 in ws).
// 64 rows/block, wave owns 16 rows.
// TRANSOUT=1 writes output transposed per batch: out[b][d][n] (for Vt).
template<int TRANSOUT>
__global__ __launch_bounds__(256) void mlp2(const float* __restrict__ X,
    const u16* __restrict__ W1t, const float* __restrict__ b1,
    const u16* __restrict__ W2t, const float* __restrict__ b2,
    u16* __restrict__ out) {
  __shared__ u16 H[64][136];            // stride 136: 16B-aligned rows, conflict-light
  const int tid = threadIdx.x;
  const int wave = tid >> 6, lane = tid & 63;
  const int c16 = lane & 15, quad = lane >> 4;
  const long row0 = (long)blockIdx.x * 64 + wave * 16;

  s8 a[4];
  {
    const float* xr = X + (row0 + c16) * D_ + quad * 8;
    #pragma unroll
    for (int kk = 0; kk < 4; kk++) a[kk] = ldcvt8(xr + kk * 32);
  }
  #pragma unroll
  for (int ns = 0; ns < 8; ns++) {
    f4 acc = {0.f, 0.f, 0.f, 0.f};
    const int c = ns * 16 + c16;
    const u16* wr = W1t + (long)c * 128 + quad * 8;
    #pragma unroll
    for (int kk = 0; kk < 4; kk++) acc = mfma16(a[kk], ld8(wr + kk * 32), acc);
    const float bias = b1[c];
    #pragma unroll
    for (int r = 0; r < 4; r++) {
      float v = acc[r] + bias;
      H[wave * 16 + quad * 4 + r][c] = f2b(v > 0.f ? v : 0.f);
    }
  }
  __syncthreads();                      // fence LDS RAW
  s8 a2[4];
  #pragma unroll
  for (int kk = 0; kk < 4; kk++)
    a2[kk] = *reinterpret_cast<const s8*>(&H[wave * 16 + c16][kk * 32 + quad * 8]);
  #pragma unroll
  for (int ns = 0; ns < 8; ns++) {
    f4 acc = {0.f, 0.f, 0.f, 0.f};
    const int c = ns * 16 + c16;
    const u16* wr = W2t + (long)c * 128 + quad * 8;
    #pragma unroll
    for (int kk = 0; kk < 4; kk++) acc = mfma16(a2[kk], ld8(wr + kk * 32), acc);
    const float bias = b2[c];
    if (TRANSOUT == 0) {
      #pragma unroll
      for (int r = 0; r < 4; r++)
        out[(row0 + quad * 4 + r) * D_ + c] = f2b(acc[r] + bias);
    } else {
      const long g = row0 + quad * 4;       // 4 consecutive rows, same batch
      const long bb = g >> 14;              // / N_
      const long n = g & (N_ - 1);
      us4 pk;
      #pragma unroll
      for (int r = 0; r < 4; r++) pk[r] = f2b(acc[r] + bias);
      *reinterpret_cast<us4*>(out + bb * (long)128 * N_ + (long)c * N_ + n) = pk;
    }
  }
}

// kpv = relu(p_feat@bW1+bb1)@bW2 + relu(|p_xyz-v_xyz|@dW1+db1)@dW2 + (bb2+db2)
__global__ __launch_bounds__(256) void kpv_kernel(
    const float* __restrict__ pf, const float* __restrict__ pxyz, const float* __restrict__ vxyz,
    const u16* __restrict__ bW1t, const float* __restrict__ bb1,
    const u16* __restrict__ bW2t, const float* __restrict__ bb2,
    const float* __restrict__ dW1, const float* __restrict__ db1,
    const u16* __restrict__ dW2t, const float* __restrict__ db2,
    u16* __restrict__ out) {
  __shared__ u16 H[64][136];
  const int tid = threadIdx.x;
  const int wave = tid >> 6, lane = tid & 63;
  const int c16 = lane & 15, quad = lane >> 4;
  const long row0 = (long)blockIdx.x * 64 + wave * 16;

  s8 a[4];
  {
    const float* xr = pf + (row0 + c16) * D_ + quad * 8;
    #pragma unroll
    for (int kk = 0; kk < 4; kk++) a[kk] = ldcvt8(xr + kk * 32);
  }
  // beta layer 1 -> H
  #pragma unroll
  for (int ns = 0; ns < 8; ns++) {
    f4 acc = {0.f, 0.f, 0.f, 0.f};
    const int c = ns * 16 + c16;
    const u16* wr = bW1t + (long)c * 128 + quad * 8;
    #pragma unroll
    for (int kk = 0; kk < 4; kk++) acc = mfma16(a[kk], ld8(wr + kk * 32), acc);
    const float bias = bb1[c];
    #pragma unroll
    for (int r = 0; r < 4; r++) {
      float v = acc[r] + bias;
      H[wave * 16 + quad * 4 + r][c] = f2b(v > 0.f ? v : 0.f);
    }
  }
  __syncthreads();                      // fence: L1 write -> L2 read
  f4 acc2[8];
  #pragma unroll
  for (int ns = 0; ns < 8; ns++) acc2[ns] = (f4){0.f, 0.f, 0.f, 0.f};
  {
    s8 a2[4];
    #pragma unroll
    for (int kk = 0; kk < 4; kk++)
      a2[kk] = *reinterpret_cast<const s8*>(&H[wave * 16 + c16][kk * 32 + quad * 8]);
    #pragma unroll
    for (int ns = 0; ns < 8; ns++) {
      const u16* wr = bW2t + (long)(ns * 16 + c16) * 128 + quad * 8;
      #pragma unroll
      for (int kk = 0; kk < 4; kk++) acc2[ns] = mfma16(a2[kk], ld8(wr + kk * 32), acc2[ns]);
    }
  }
  __syncthreads();                      // fence: beta read -> delta overwrite (WAR)
  // delta hidden (Din=3, VALU) -> overwrite own H rows
  {
    const long bat = ((long)blockIdx.x * 64) / N_;
    const float vx0 = vxyz[bat * 3 + 0];
    const float vx1 = vxyz[bat * 3 + 1];
    const float vx2 = vxyz[bat * 3 + 2];
    for (int i = 0; i < 32; i++) {
      const int e = lane + 64 * i;
      const int rr = e >> 7, cc = e & 127;
      const long gr = row0 + rr;
      const float d0 = fabsf(pxyz[gr * 3 + 0] - vx0);
      const float d1 = fabsf(pxyz[gr * 3 + 1] - vx1);
      const float d2 = fabsf(pxyz[gr * 3 + 2] - vx2);
      float h = d0 * dW1[cc] + d1 * dW1[128 + cc] + d2 * dW1[256 + cc] + db1[cc];
      H[wave * 16 + rr][cc] = f2b(h > 0.f ? h : 0.f);
    }
  }
  __syncthreads();                      // fence: delta write -> delta read
  {
    s8 a2[4];
    #pragma unroll
    for (int kk = 0; kk < 4; kk++)
      a2[kk] = *reinterpret_cast<const s8*>(&H[wave * 16 + c16][kk * 32 + quad * 8]);
    #pragma unroll
    for (int ns = 0; ns < 8; ns++) {
      const u16* wr = dW2t + (long)(ns * 16 + c16) * 128 + quad * 8;
      #pragma unroll
      for (int kk = 0; kk < 4; kk++) acc2[ns] = mfma16(a2[kk], ld8(wr + kk * 32), acc2[ns]);
    }
  }
  #pragma unroll
  for (int ns = 0; ns < 8; ns++) {
    const int c = ns * 16 + c16;
    const float bias = bb2[c] + db2[c];
    #pragma unroll
    for (int r = 0; r < 4; r++)
      out[(row0 + quad * 4 + r) * D_ + c] = f2b(acc2[ns][r] + bias);
  }
}

// Pass 1: inv_colsum[b,n] = 1 / sum_m exp(q[m]·kpv[n]*scale). Wave owns 16 n-cols.
__global__ __launch_bounds__(256) void colsum_k(const u16* __restrict__ q,
    const u16* __restrict__ kpv, float* __restrict__ inv) {
  const int tid = threadIdx.x;
  const int wave = tid >> 6, lane = tid & 63;
  const int c16 = lane & 15, quad = lane >> 4;
  const int b = blockIdx.x >> 8;                 // 256 blocks per batch
  const int nb = (blockIdx.x & 255) * 64 + wave * 16;
  s8 bk[4];
  {
    const u16* kr = kpv + ((long)b * N_ + nb + c16) * D_ + quad * 8;
    #pragma unroll
    for (int kk = 0; kk < 4; kk++) bk[kk] = ld8(kr + kk * 32);
  }
  const float scale = 0.088388347648318447f;     // 1/sqrt(128)
  float sum = 0.f;
  const u16* qb = q + (long)b * M_ * D_;
  for (int m0 = 0; m0 < M_; m0 += 32) {
    #pragma unroll
    for (int ms = 0; ms < 2; ms++) {
      const u16* qr = qb + (long)(m0 + ms * 16 + c16) * D_ + quad * 8;
      f4 acc = {0.f, 0.f, 0.f, 0.f};
      #pragma unroll
      for (int kk = 0; kk < 4; kk++) acc = mfma16(ld8(qr + kk * 32), bk[kk], acc);
      #pragma unroll
      for (int r = 0; r < 4; r++) sum += __expf(clamp50(acc[r] * scale));
    }
  }
  sum += __shfl_xor(sum, 16, 64);
  sum += __shfl_xor(sum, 32, 64);
  if (lane < 16) inv[(long)b * N_ + nb + lane] = 1.f / sum;
}

// Pass 2a (barrier-free): partial[bid][64m][128d] = sum_{n in slice} P^T V.
// S^T tile via MFMA (A=KPV frag, B=Q frag): C layout col=m, row=n(quad*4+r).
// Two 16-n chunks pack into one K=32 B-frag (j=0..3 chunk0, j=4..7 chunk1);
// Vt 8B slots at n0+quad*4 / n0+16+quad*4 form the matching A-frag.
__global__ __launch_bounds__(256) void attn_part(const u16* __restrict__ q,
    const u16* __restrict__ kpv, const u16* __restrict__ vt,
    const float* __restrict__ inv, float* __restrict__ part) {
  const int tid = threadIdx.x;
  const int wave = tid >> 6, lane = tid & 63;
  const int c16 = lane & 15, quad = lane >> 4;
  const int bid = blockIdx.x;                    // b(2) x mb(64) x ns(4)
  const int ns = bid & (NSPLIT - 1);
  const int mb = (bid >> 2) & 63;
  const int b = bid >> 8;
  const int m0 = mb * 64 + wave * 16;
  const int n_begin = ns * (N_ / NSPLIT);
  const float scale = 0.088388347648318447f;

  s8 bq[4];                                      // Q as B-operand (same frag pattern)
  {
    const u16* qr = q + ((long)b * M_ + m0 + c16) * D_ + quad * 8;
    #pragma unroll
    for (int kk = 0; kk < 4; kk++) bq[kk] = ld8(qr + kk * 32);
  }
  f4 acc[8];                                     // O^T: col=m, row=d (8 d-blocks)
  #pragma unroll
  for (int db = 0; db < 8; db++) acc[db] = (f4){0.f, 0.f, 0.f, 0.f};

  const u16* kpb = kpv + (long)b * N_ * D_;
  const u16* vtb = vt + (long)b * (long)D_ * N_;
  const float* invb = inv + (long)b * N_;

  for (int n0 = n_begin; n0 < n_begin + N_ / NSPLIT; n0 += 32) {
    // S^T for two 16-n chunks
    const u16* kr0 = kpb + (long)(n0 + c16) * D_ + quad * 8;
    const u16* kr1 = kpb + (long)(n0 + 16 + c16) * D_ + quad * 8;
    f4 st0 = {0.f, 0.f, 0.f, 0.f}, st1 = {0.f, 0.f, 0.f, 0.f};
    #pragma unroll
    for (int kk = 0; kk < 4; kk++) st0 = mfma16(ld8(kr0 + kk * 32), bq[kk], st0);
    #pragma unroll
    for (int kk = 0; kk < 4; kk++) st1 = mfma16(ld8(kr1 + kk * 32), bq[kk], st1);
    const f4 ic0 = *reinterpret_cast<const f4*>(invb + n0 + quad * 4);
    const f4 ic1 = *reinterpret_cast<const f4*>(invb + n0 + 16 + quad * 4);
    s8 pfrag;
    #pragma unroll
    for (int r = 0; r < 4; r++) {
      pfrag[r]     = (short)f2b(__expf(clamp50(st0[r] * scale)) * ic0[r]);
      pfrag[4 + r] = (short)f2b(__expf(clamp50(st1[r] * scale)) * ic1[r]);
    }
    // PV: A = Vt frag (two 8B slots), B = pfrag
    #pragma unroll
    for (int db = 0; db < 8; db++) {
      const u16* vr = vtb + (long)(db * 16 + c16) * N_ + n0 + quad * 4;
      us4 lo = *reinterpret_cast<const us4*>(vr);
      us4 hi = *reinterpret_cast<const us4*>(vr + 16);
      s8 av;
      #pragma unroll
      for (int j = 0; j < 4; j++) { av[j] = (short)lo[j]; av[4 + j] = (short)hi[j]; }
      acc[db] = mfma16(av, pfrag, acc[db]);
    }
  }
  // store partial tile [64m][128d] f32
  float* pt = part + (long)bid * 64 * 128 + (wave * 16 + c16) * 128;
  #pragma unroll
  for (int db = 0; db < 8; db++)
    *reinterpret_cast<f4*>(pt + db * 16 + quad * 4) = acc[db];
}

// Pass 2b: out = sum_ns partial + vfeat  (f32 out)
__global__ __launch_bounds__(256) void attn_reduce(const float* __restrict__ part,
    const float* __restrict__ vfeat, float* __restrict__ out) {
  const int g4 = blockIdx.x * 256 + threadIdx.x;     // 0 .. B*M*D/4-1
  const int b = g4 >> 17;                            // M*D/4 = 131072
  const int rem = g4 & 131071;
  const int m = rem >> 5;
  const int d4 = rem & 31;
  const int mb = m >> 6, mr = m & 63;
  const long base = ((long)(b * 256 + mb * 4)) * 8192 + mr * 128 + d4 * 4;
  f4 s = *reinterpret_cast<const f4*>(vfeat + (long)g4 * 4);
  #pragma unroll
  for (int ns = 0; ns < NSPLIT; ns++)
    s += *reinterpret_cast<const f4*>(part + base + ns * 8192);
  *reinterpret_cast<f4*>(out + (long)g4 * 4) = s;
}

extern "C" void kernel_launch(void* const* d_in, const int* in_sizes, int n_in,
                              void* d_out, int out_size, void* d_ws, size_t ws_size,
                              hipStream_t stream) {
  const float* p_xyz  = (const float*)d_in[0];
  const float* v_xyz  = (const float*)d_in[1];
  const float* p_feat = (const float*)d_in[2];
  const float* v_feat = (const float*)d_in[3];
  const float* aW1 = (const float*)d_in[4],  *ab1 = (const float*)d_in[5];
  const float* aW2 = (const float*)d_in[6],  *ab2 = (const float*)d_in[7];
  const float* bW1 = (const float*)d_in[8],  *bb1 = (const float*)d_in[9];
  const float* bW2 = (const float*)d_in[10], *bb2 = (const float*)d_in[11];
  const float* oW1 = (const float*)d_in[12], *ob1 = (const float*)d_in[13];
  const float* oW2 = (const float*)d_in[14], *ob2 = (const float*)d_in[15];
  const float* dW1 = (const float*)d_in[16], *db1 = (const float*)d_in[17];
  const float* dW2 = (const float*)d_in[18], *db2 = (const float*)d_in[19];

  char* ws = (char*)d_ws;
  u16* wt    = (u16*)ws;                               // 7 * 16384 bf16 elems
  u16* aW1t  = wt + 0 * 16384;
  u16* aW2t  = wt + 1 * 16384;
  u16* bW1t  = wt + 2 * 16384;
  u16* bW2t  = wt + 3 * 16384;
  u16* oW1t  = wt + 4 * 16384;
  u16* oW2t  = wt + 5 * 16384;
  u16* dW2t  = wt + 6 * 16384;
  u16* qbuf  = (u16*)(ws + 262144);                    // B*M*D bf16 = 2 MB
  u16* kpvb  = (u16*)(ws + 2359296);                   // B*N*D bf16 = 8 MB
  u16* vtb   = (u16*)(ws + 10747904);                  // Vt = 8 MB
  float* invb = (float*)(ws + 19136512);               // B*N f32 = 128 KB
  float* partb = (float*)(ws + 19267584);              // B*M*D*NSPLIT f32 = 16 MB

  wtrans<<<dim3(7), dim3(256), 0, stream>>>(aW1, aW2, bW1, bW2, oW1, oW2, dW2, wt);
  mlp2<0><<<dim3((B_ * M_) / 64), dim3(256), 0, stream>>>(v_feat, aW1t, ab1, aW2t, ab2, qbuf);
  mlp2<1><<<dim3((B_ * N_) / 64), dim3(256), 0, stream>>>(p_feat, oW1t, ob1, oW2t, ob2, vtb);
  kpv_kernel<<<dim3((B_ * N_) / 64), dim3(256), 0, stream>>>(
      p_feat, p_xyz, v_xyz, bW1t, bb1, bW2t, bb2, dW1, db1, dW2t, db2, kpvb);
  colsum_k<<<dim3(B_ * (N_ / 64)), dim3(256), 0, stream>>>(qbuf, kpvb, invb);
  attn_part<<<dim3(B_ * 64 * NSPLIT), dim3(256), 0, stream>>>(qbuf, kpvb, vtb, invb, partb);
  attn_reduce<<<dim3((B_ * M_ * D_ / 4) / 256), dim3(256), 0, stream>>>(partb, v_feat,
                                                                        (float*)d_out);
}

// Round 5
// 724.186 us; speedup vs baseline: 1.5143x; 1.5143x over previous
//
#include <hip/hip_runtime.h>

#define B_ 2
#define N_ 16384
#define M_ 4096
#define D_ 128
#define NSPLIT 4

typedef __attribute__((ext_vector_type(8))) short s8;     // 8 bf16 (4 VGPRs)
typedef __attribute__((ext_vector_type(4))) float f4;     // MFMA C/D + float4 loads
typedef __attribute__((ext_vector_type(4))) unsigned short us4;
typedef unsigned short u16;

__device__ __forceinline__ u16 f2b(float f) {   // RNE float->bf16
  unsigned int x = __float_as_uint(f);
  unsigned int r = x + 0x7fffu + ((x >> 16) & 1u);
  return (u16)(r >> 16);
}
__device__ __forceinline__ s8 ld8(const u16* p) {
  return *reinterpret_cast<const s8*>(p);
}
// Load 8 consecutive f32 (32B, 16B-aligned) and convert to 8 bf16 lanes.
__device__ __forceinline__ s8 ldcvt8(const float* p) {
  f4 x = *reinterpret_cast<const f4*>(p);
  f4 y = *reinterpret_cast<const f4*>(p + 4);
  s8 r;
  r[0] = (short)f2b(x[0]); r[1] = (short)f2b(x[1]);
  r[2] = (short)f2b(x[2]); r[3] = (short)f2b(x[3]);
  r[4] = (short)f2b(y[0]); r[5] = (short)f2b(y[1]);
  r[6] = (short)f2b(y[2]); r[7] = (short)f2b(y[3]);
  return r;
}
__device__ __forceinline__ f4 mfma16(s8 a, s8 b, f4 c) {
  return __builtin_amdgcn_mfma_f32_16x16x32_bf16(a, b, c, 0, 0, 0);
}
__device__ __forceinline__ float clamp50(float x) {
  return fminf(fmaxf(x, -50.f), 50.f);
}

// Transpose seven 128x128 f32 weight matrices into ws as bf16 Wt[n][k] (B-frags).
__global__ void wtrans(const float* a0, const float* a1, const float* a2, const float* a3,
                       const float* a4, const float* a5, const float* a6, u16* dst) {
  const float* s;
  switch (blockIdx.x) {
    case 0: s = a0; break; case 1: s = a1; break; case 2: s = a2; break;
    case 3: s = a3; break; case 4: s = a4; break; case 5: s = a5; break;
    default: s = a6; break;
  }
  u16* d = dst + blockIdx.x * 16384;
  for (int i = threadIdx.x; i < 16384; i += 256) {
    int r = i >> 7, c = i & 127;
    d[c * 128 + r] = f2b(s[i]);
  }
}

// Fused 2-layer MLP: out = relu(X@W1+b1)@W2+b2 (X f32, out bf16 in ws).
// 64 rows/block, wave owns 16 rows.
// TRANSOUT=1 writes output transposed per batch: out[b][d][n] (for Vt).
template<int TRANSOUT>
__global__ __launch_bounds__(256) void mlp2(const float* __restrict__ X,
    const u16* __restrict__ W1t, const float* __restrict__ b1,
    const u16* __restrict__ W2t, const float* __restrict__ b2,
    u16* __restrict__ out) {
  __shared__ u16 H[64][136];
  const int tid = threadIdx.x;
  const int wave = tid >> 6, lane = tid & 63;
  const int c16 = lane & 15, quad = lane >> 4;
  const long row0 = (long)blockIdx.x * 64 + wave * 16;

  s8 a[4];
  {
    const float* xr = X + (row0 + c16) * D_ + quad * 8;
    #pragma unroll
    for (int kk = 0; kk < 4; kk++) a[kk] = ldcvt8(xr + kk * 32);
  }
  #pragma unroll
  for (int ns = 0; ns < 8; ns++) {
    f4 acc = {0.f, 0.f, 0.f, 0.f};
    const int c = ns * 16 + c16;
    const u16* wr = W1t + (long)c * 128 + quad * 8;
    #pragma unroll
    for (int kk = 0; kk < 4; kk++) acc = mfma16(a[kk], ld8(wr + kk * 32), acc);
    const float bias = b1[c];
    #pragma unroll
    for (int r = 0; r < 4; r++) {
      float v = acc[r] + bias;
      H[wave * 16 + quad * 4 + r][c] = f2b(v > 0.f ? v : 0.f);
    }
  }
  __syncthreads();
  s8 a2[4];
  #pragma unroll
  for (int kk = 0; kk < 4; kk++)
    a2[kk] = *reinterpret_cast<const s8*>(&H[wave * 16 + c16][kk * 32 + quad * 8]);
  #pragma unroll
  for (int ns = 0; ns < 8; ns++) {
    f4 acc = {0.f, 0.f, 0.f, 0.f};
    const int c = ns * 16 + c16;
    const u16* wr = W2t + (long)c * 128 + quad * 8;
    #pragma unroll
    for (int kk = 0; kk < 4; kk++) acc = mfma16(a2[kk], ld8(wr + kk * 32), acc);
    const float bias = b2[c];
    if (TRANSOUT == 0) {
      #pragma unroll
      for (int r = 0; r < 4; r++)
        out[(row0 + quad * 4 + r) * D_ + c] = f2b(acc[r] + bias);
    } else {
      const long g = row0 + quad * 4;
      const long bb = g >> 14;
      const long n = g & (N_ - 1);
      us4 pk;
      #pragma unroll
      for (int r = 0; r < 4; r++) pk[r] = f2b(acc[r] + bias);
      *reinterpret_cast<us4*>(out + bb * (long)128 * N_ + (long)c * N_ + n) = pk;
    }
  }
}

// kpv = relu(p_feat@bW1+bb1)@bW2 + relu(|p_xyz-v_xyz|@dW1+db1)@dW2 + (bb2+db2)
__global__ __launch_bounds__(256) void kpv_kernel(
    const float* __restrict__ pf, const float* __restrict__ pxyz, const float* __restrict__ vxyz,
    const u16* __restrict__ bW1t, const float* __restrict__ bb1,
    const u16* __restrict__ bW2t, const float* __restrict__ bb2,
    const float* __restrict__ dW1, const float* __restrict__ db1,
    const u16* __restrict__ dW2t, const float* __restrict__ db2,
    u16* __restrict__ out) {
  __shared__ u16 H[64][136];
  const int tid = threadIdx.x;
  const int wave = tid >> 6, lane = tid & 63;
  const int c16 = lane & 15, quad = lane >> 4;
  const long row0 = (long)blockIdx.x * 64 + wave * 16;

  s8 a[4];
  {
    const float* xr = pf + (row0 + c16) * D_ + quad * 8;
    #pragma unroll
    for (int kk = 0; kk < 4; kk++) a[kk] = ldcvt8(xr + kk * 32);
  }
  #pragma unroll
  for (int ns = 0; ns < 8; ns++) {
    f4 acc = {0.f, 0.f, 0.f, 0.f};
    const int c = ns * 16 + c16;
    const u16* wr = bW1t + (long)c * 128 + quad * 8;
    #pragma unroll
    for (int kk = 0; kk < 4; kk++) acc = mfma16(a[kk], ld8(wr + kk * 32), acc);
    const float bias = bb1[c];
    #pragma unroll
    for (int r = 0; r < 4; r++) {
      float v = acc[r] + bias;
      H[wave * 16 + quad * 4 + r][c] = f2b(v > 0.f ? v : 0.f);
    }
  }
  __syncthreads();
  f4 acc2[8];
  #pragma unroll
  for (int ns = 0; ns < 8; ns++) acc2[ns] = (f4){0.f, 0.f, 0.f, 0.f};
  {
    s8 a2[4];
    #pragma unroll
    for (int kk = 0; kk < 4; kk++)
      a2[kk] = *reinterpret_cast<const s8*>(&H[wave * 16 + c16][kk * 32 + quad * 8]);
    #pragma unroll
    for (int ns = 0; ns < 8; ns++) {
      const u16* wr = bW2t + (long)(ns * 16 + c16) * 128 + quad * 8;
      #pragma unroll
      for (int kk = 0; kk < 4; kk++) acc2[ns] = mfma16(a2[kk], ld8(wr + kk * 32), acc2[ns]);
    }
  }
  __syncthreads();
  {
    const long bat = ((long)blockIdx.x * 64) / N_;
    const float vx0 = vxyz[bat * 3 + 0];
    const float vx1 = vxyz[bat * 3 + 1];
    const float vx2 = vxyz[bat * 3 + 2];
    for (int i = 0; i < 32; i++) {
      const int e = lane + 64 * i;
      const int rr = e >> 7, cc = e & 127;
      const long gr = row0 + rr;
      const float d0 = fabsf(pxyz[gr * 3 + 0] - vx0);
      const float d1 = fabsf(pxyz[gr * 3 + 1] - vx1);
      const float d2 = fabsf(pxyz[gr * 3 + 2] - vx2);
      float h = d0 * dW1[cc] + d1 * dW1[128 + cc] + d2 * dW1[256 + cc] + db1[cc];
      H[wave * 16 + rr][cc] = f2b(h > 0.f ? h : 0.f);
    }
  }
  __syncthreads();
  {
    s8 a2[4];
    #pragma unroll
    for (int kk = 0; kk < 4; kk++)
      a2[kk] = *reinterpret_cast<const s8*>(&H[wave * 16 + c16][kk * 32 + quad * 8]);
    #pragma unroll
    for (int ns = 0; ns < 8; ns++) {
      const u16* wr = dW2t + (long)(ns * 16 + c16) * 128 + quad * 8;
      #pragma unroll
      for (int kk = 0; kk < 4; kk++) acc2[ns] = mfma16(a2[kk], ld8(wr + kk * 32), acc2[ns]);
    }
  }
  #pragma unroll
  for (int ns = 0; ns < 8; ns++) {
    const int c = ns * 16 + c16;
    const float bias = bb2[c] + db2[c];
    #pragma unroll
    for (int r = 0; r < 4; r++)
      out[(row0 + quad * 4 + r) * D_ + c] = f2b(acc2[ns][r] + bias);
  }
}

// Pass 1: inv_colsum[b,n] = 1 / sum_m exp(q[m]·kpv[n]*scale). Wave owns 16 n-cols.
// m-loop unrolled x64: 16 independent Q loads in flight per iteration.
__global__ __launch_bounds__(256) void colsum_k(const u16* __restrict__ q,
    const u16* __restrict__ kpv, float* __restrict__ inv) {
  const int tid = threadIdx.x;
  const int wave = tid >> 6, lane = tid & 63;
  const int c16 = lane & 15, quad = lane >> 4;
  const int b = blockIdx.x >> 8;
  const int nb = (blockIdx.x & 255) * 64 + wave * 16;
  s8 bk[4];
  {
    const u16* kr = kpv + ((long)b * N_ + nb + c16) * D_ + quad * 8;
    #pragma unroll
    for (int kk = 0; kk < 4; kk++) bk[kk] = ld8(kr + kk * 32);
  }
  const float scale = 0.088388347648318447f;     // 1/sqrt(128)
  float sum = 0.f;
  const u16* qb = q + (long)b * M_ * D_;
  for (int m0 = 0; m0 < M_; m0 += 64) {
    s8 qa[4][4];
    #pragma unroll
    for (int ms = 0; ms < 4; ms++) {
      const u16* qr = qb + (long)(m0 + ms * 16 + c16) * D_ + quad * 8;
      #pragma unroll
      for (int kk = 0; kk < 4; kk++) qa[ms][kk] = ld8(qr + kk * 32);
    }
    f4 acc[4];
    #pragma unroll
    for (int ms = 0; ms < 4; ms++) {
      acc[ms] = (f4){0.f, 0.f, 0.f, 0.f};
      #pragma unroll
      for (int kk = 0; kk < 4; kk++) acc[ms] = mfma16(qa[ms][kk], bk[kk], acc[ms]);
    }
    #pragma unroll
    for (int ms = 0; ms < 4; ms++)
      #pragma unroll
      for (int r = 0; r < 4; r++) sum += __expf(clamp50(acc[ms][r] * scale));
  }
  sum += __shfl_xor(sum, 16, 64);
  sum += __shfl_xor(sum, 32, 64);
  if (lane < 16) inv[(long)b * N_ + nb + lane] = 1.f / sum;
}

// Pass 2a: partial[bid][64m][128d] over n-slice. 512 threads (8 waves).
// S-phase: wave (msub 0..3, nhalf 0..1) computes 16m x 32n scores (r3-verified
// mappings), scaled P -> LDS. PV-phase: wave owns 16 d; A=P from LDS, B=Vt.
__global__ __launch_bounds__(512, 4) void attn_v3(const u16* __restrict__ q,
    const u16* __restrict__ kpv, const u16* __restrict__ vt,
    const float* __restrict__ inv, float* __restrict__ part) {
  __shared__ u16 P[64][72];                      // 9216 B, 2-way-free banking
  const int tid = threadIdx.x;
  const int wave = tid >> 6, lane = tid & 63;
  const int c16 = lane & 15, quad = lane >> 4;
  const int bid = blockIdx.x;                    // b(2) x mb(64) x ns(4)
  const int ns = bid & (NSPLIT - 1);
  const int mb = (bid >> 2) & 63;
  const int b = bid >> 8;
  const int msub = wave & 3;
  const int nhalf = wave >> 2;
  const int m_base = mb * 64;
  const int dbase = wave * 16;
  const int n_begin = ns * (N_ / NSPLIT);
  const float scale = 0.088388347648318447f;

  s8 aq[4];                                      // Q A-frag for wave's 16 m-rows
  {
    const u16* qr = q + ((long)b * M_ + m_base + msub * 16 + c16) * D_ + quad * 8;
    #pragma unroll
    for (int kk = 0; kk < 4; kk++) aq[kk] = ld8(qr + kk * 32);
  }
  f4 acc[4];                                     // O tile: 4 m-tiles x wave's 16 d
  #pragma unroll
  for (int i = 0; i < 4; i++) acc[i] = (f4){0.f, 0.f, 0.f, 0.f};

  const u16* kpb = kpv + (long)b * N_ * D_;
  const u16* vtb = vt + (long)b * (long)D_ * N_;
  const float* invb = inv + (long)b * N_;

  for (int n0 = n_begin; n0 < n_begin + N_ / NSPLIT; n0 += 64) {
    #pragma unroll
    for (int t = 0; t < 2; t++) {
      const int nc = n0 + nhalf * 32 + t * 16 + c16;
      const u16* kr = kpb + (long)nc * D_ + quad * 8;
      f4 as = {0.f, 0.f, 0.f, 0.f};
      #pragma unroll
      for (int kk = 0; kk < 4; kk++) as = mfma16(aq[kk], ld8(kr + kk * 32), as);
      const float ic = invb[nc];
      #pragma unroll
      for (int r = 0; r < 4; r++)
        P[msub * 16 + quad * 4 + r][nhalf * 32 + t * 16 + c16] =
            f2b(__expf(clamp50(as[r] * scale)) * ic);
    }
    __syncthreads();
    // PV: each wave covers all 64 m for its 16 d columns
    s8 bv[2];
    {
      const u16* vr = vtb + (long)(dbase + c16) * N_ + n0 + quad * 8;
      bv[0] = ld8(vr);
      bv[1] = ld8(vr + 32);
    }
    #pragma unroll
    for (int i = 0; i < 4; i++) {
      #pragma unroll
      for (int kk = 0; kk < 2; kk++) {
        s8 ap = *reinterpret_cast<const s8*>(&P[i * 16 + c16][kk * 32 + quad * 8]);
        acc[i] = mfma16(ap, bv[kk], acc[i]);
      }
    }
    __syncthreads();
  }
  // store partial tile [64m][128d] f32; C/D: col=c16 (d), row=quad*4+r (m)
  float* pt = part + (long)bid * 64 * 128;
  #pragma unroll
  for (int i = 0; i < 4; i++)
    #pragma unroll
    for (int r = 0; r < 4; r++)
      pt[(i * 16 + quad * 4 + r) * 128 + dbase + c16] = acc[i][r];
}

// Pass 2b: out = sum_ns partial + vfeat  (f32 out)
__global__ __launch_bounds__(256) void attn_reduce(const float* __restrict__ part,
    const float* __restrict__ vfeat, float* __restrict__ out) {
  const int g4 = blockIdx.x * 256 + threadIdx.x;     // 0 .. B*M*D/4-1
  const int b = g4 >> 17;                            // M*D/4 = 131072
  const int rem = g4 & 131071;
  const int m = rem >> 5;
  const int d4 = rem & 31;
  const int mb = m >> 6, mr = m & 63;
  const long base = ((long)(b * 256 + mb * 4)) * 8192 + mr * 128 + d4 * 4;
  f4 s = *reinterpret_cast<const f4*>(vfeat + (long)g4 * 4);
  #pragma unroll
  for (int ns = 0; ns < NSPLIT; ns++)
    s += *reinterpret_cast<const f4*>(part + base + ns * 8192);
  *reinterpret_cast<f4*>(out + (long)g4 * 4) = s;
}

extern "C" void kernel_launch(void* const* d_in, const int* in_sizes, int n_in,
                              void* d_out, int out_size, void* d_ws, size_t ws_size,
                              hipStream_t stream) {
  const float* p_xyz  = (const float*)d_in[0];
  const float* v_xyz  = (const float*)d_in[1];
  const float* p_feat = (const float*)d_in[2];
  const float* v_feat = (const float*)d_in[3];
  const float* aW1 = (const float*)d_in[4],  *ab1 = (const float*)d_in[5];
  const float* aW2 = (const float*)d_in[6],  *ab2 = (const float*)d_in[7];
  const float* bW1 = (const float*)d_in[8],  *bb1 = (const float*)d_in[9];
  const float* bW2 = (const float*)d_in[10], *bb2 = (const float*)d_in[11];
  const float* oW1 = (const float*)d_in[12], *ob1 = (const float*)d_in[13];
  const float* oW2 = (const float*)d_in[14], *ob2 = (const float*)d_in[15];
  const float* dW1 = (const float*)d_in[16], *db1 = (const float*)d_in[17];
  const float* dW2 = (const float*)d_in[18], *db2 = (const float*)d_in[19];

  char* ws = (char*)d_ws;
  u16* wt    = (u16*)ws;                               // 7 * 16384 bf16 elems
  u16* aW1t  = wt + 0 * 16384;
  u16* aW2t  = wt + 1 * 16384;
  u16* bW1t  = wt + 2 * 16384;
  u16* bW2t  = wt + 3 * 16384;
  u16* oW1t  = wt + 4 * 16384;
  u16* oW2t  = wt + 5 * 16384;
  u16* dW2t  = wt + 6 * 16384;
  u16* qbuf  = (u16*)(ws + 262144);                    // B*M*D bf16 = 2 MB
  u16* kpvb  = (u16*)(ws + 2359296);                   // B*N*D bf16 = 8 MB
  u16* vtb   = (u16*)(ws + 10747904);                  // Vt = 8 MB
  float* invb = (float*)(ws + 19136512);               // B*N f32 = 128 KB
  float* partb = (float*)(ws + 19267584);              // B*M*D*NSPLIT f32 = 16 MB

  wtrans<<<dim3(7), dim3(256), 0, stream>>>(aW1, aW2, bW1, bW2, oW1, oW2, dW2, wt);
  mlp2<0><<<dim3((B_ * M_) / 64), dim3(256), 0, stream>>>(v_feat, aW1t, ab1, aW2t, ab2, qbuf);
  mlp2<1><<<dim3((B_ * N_) / 64), dim3(256), 0, stream>>>(p_feat, oW1t, ob1, oW2t, ob2, vtb);
  kpv_kernel<<<dim3((B_ * N_) / 64), dim3(256), 0, stream>>>(
      p_feat, p_xyz, v_xyz, bW1t, bb1, bW2t, bb2, dW1, db1, dW2t, db2, kpvb);
  colsum_k<<<dim3(B_ * (N_ / 64)), dim3(256), 0, stream>>>(qbuf, kpvb, invb);
  attn_v3<<<dim3(B_ * 64 * NSPLIT), dim3(512), 0, stream>>>(qbuf, kpvb, vtb, invb, partb);
  attn_reduce<<<dim3((B_ * M_ * D_ / 4) / 256), dim3(256), 0, stream>>>(partb, v_feat,
                                                                        (float*)d_out);
}

// Round 6
// 708.591 us; speedup vs baseline: 1.5477x; 1.0220x over previous
//
#include <hip/hip_runtime.h>

#define B_ 2
#define N_ 16384
#define M_ 4096
#define D_ 128

typedef __attribute__((ext_vector_type(8))) short s8;     // 8 bf16 (4 VGPRs)
typedef __attribute__((ext_vector_type(4))) float f4;     // MFMA C/D + float4 loads
typedef __attribute__((ext_vector_type(4))) unsigned short us4;
typedef unsigned short u16;

__device__ __forceinline__ u16 f2b(float f) {   // RNE float->bf16
  unsigned int x = __float_as_uint(f);
  unsigned int r = x + 0x7fffu + ((x >> 16) & 1u);
  return (u16)(r >> 16);
}
__device__ __forceinline__ s8 ld8(const u16* p) {
  return *reinterpret_cast<const s8*>(p);
}
// Load 8 consecutive f32 (32B, 16B-aligned) and convert to 8 bf16 lanes.
__device__ __forceinline__ s8 ldcvt8(const float* p) {
  f4 x = *reinterpret_cast<const f4*>(p);
  f4 y = *reinterpret_cast<const f4*>(p + 4);
  s8 r;
  r[0] = (short)f2b(x[0]); r[1] = (short)f2b(x[1]);
  r[2] = (short)f2b(x[2]); r[3] = (short)f2b(x[3]);
  r[4] = (short)f2b(y[0]); r[5] = (short)f2b(y[1]);
  r[6] = (short)f2b(y[2]); r[7] = (short)f2b(y[3]);
  return r;
}
__device__ __forceinline__ f4 mfma16(s8 a, s8 b, f4 c) {
  return __builtin_amdgcn_mfma_f32_16x16x32_bf16(a, b, c, 0, 0, 0);
}
// scale * log2(e): exp(s/sqrt(128)) == exp2(s * CS)
#define CS 0.1275174365f

// Transpose seven 128x128 f32 weight matrices into ws as bf16 Wt[n][k] (B-frags).
__global__ void wtrans(const float* a0, const float* a1, const float* a2, const float* a3,
                       const float* a4, const float* a5, const float* a6, u16* dst) {
  const float* s;
  switch (blockIdx.x) {
    case 0: s = a0; break; case 1: s = a1; break; case 2: s = a2; break;
    case 3: s = a3; break; case 4: s = a4; break; case 5: s = a5; break;
    default: s = a6; break;
  }
  u16* d = dst + blockIdx.x * 16384;
  for (int i = threadIdx.x; i < 16384; i += 256) {
    int r = i >> 7, c = i & 127;
    d[c * 128 + r] = f2b(s[i]);
  }
}

// Fused 2-layer MLP: out = relu(X@W1+b1)@W2+b2 (X f32, out bf16 in ws).
template<int TRANSOUT>
__global__ __launch_bounds__(256) void mlp2(const float* __restrict__ X,
    const u16* __restrict__ W1t, const float* __restrict__ b1,
    const u16* __restrict__ W2t, const float* __restrict__ b2,
    u16* __restrict__ out) {
  __shared__ u16 H[64][136];
  const int tid = threadIdx.x;
  const int wave = tid >> 6, lane = tid & 63;
  const int c16 = lane & 15, quad = lane >> 4;
  const long row0 = (long)blockIdx.x * 64 + wave * 16;

  s8 a[4];
  {
    const float* xr = X + (row0 + c16) * D_ + quad * 8;
    #pragma unroll
    for (int kk = 0; kk < 4; kk++) a[kk] = ldcvt8(xr + kk * 32);
  }
  #pragma unroll
  for (int ns = 0; ns < 8; ns++) {
    f4 acc = {0.f, 0.f, 0.f, 0.f};
    const int c = ns * 16 + c16;
    const u16* wr = W1t + (long)c * 128 + quad * 8;
    #pragma unroll
    for (int kk = 0; kk < 4; kk++) acc = mfma16(a[kk], ld8(wr + kk * 32), acc);
    const float bias = b1[c];
    #pragma unroll
    for (int r = 0; r < 4; r++) {
      float v = acc[r] + bias;
      H[wave * 16 + quad * 4 + r][c] = f2b(v > 0.f ? v : 0.f);
    }
  }
  __syncthreads();
  s8 a2[4];
  #pragma unroll
  for (int kk = 0; kk < 4; kk++)
    a2[kk] = *reinterpret_cast<const s8*>(&H[wave * 16 + c16][kk * 32 + quad * 8]);
  #pragma unroll
  for (int ns = 0; ns < 8; ns++) {
    f4 acc = {0.f, 0.f, 0.f, 0.f};
    const int c = ns * 16 + c16;
    const u16* wr = W2t + (long)c * 128 + quad * 8;
    #pragma unroll
    for (int kk = 0; kk < 4; kk++) acc = mfma16(a2[kk], ld8(wr + kk * 32), acc);
    const float bias = b2[c];
    if (TRANSOUT == 0) {
      #pragma unroll
      for (int r = 0; r < 4; r++)
        out[(row0 + quad * 4 + r) * D_ + c] = f2b(acc[r] + bias);
    } else {
      const long g = row0 + quad * 4;
      const long bb = g >> 14;
      const long n = g & (N_ - 1);
      us4 pk;
      #pragma unroll
      for (int r = 0; r < 4; r++) pk[r] = f2b(acc[r] + bias);
      *reinterpret_cast<us4*>(out + bb * (long)128 * N_ + (long)c * N_ + n) = pk;
    }
  }
}

// kpv = relu(p_feat@bW1+bb1)@bW2 + relu(|p_xyz-v_xyz|@dW1+db1)@dW2 + (bb2+db2)
__global__ __launch_bounds__(256) void kpv_kernel(
    const float* __restrict__ pf, const float* __restrict__ pxyz, const float* __restrict__ vxyz,
    const u16* __restrict__ bW1t, const float* __restrict__ bb1,
    const u16* __restrict__ bW2t, const float* __restrict__ bb2,
    const float* __restrict__ dW1, const float* __restrict__ db1,
    const u16* __restrict__ dW2t, const float* __restrict__ db2,
    u16* __restrict__ out) {
  __shared__ u16 H[64][136];
  const int tid = threadIdx.x;
  const int wave = tid >> 6, lane = tid & 63;
  const int c16 = lane & 15, quad = lane >> 4;
  const long row0 = (long)blockIdx.x * 64 + wave * 16;

  s8 a[4];
  {
    const float* xr = pf + (row0 + c16) * D_ + quad * 8;
    #pragma unroll
    for (int kk = 0; kk < 4; kk++) a[kk] = ldcvt8(xr + kk * 32);
  }
  #pragma unroll
  for (int ns = 0; ns < 8; ns++) {
    f4 acc = {0.f, 0.f, 0.f, 0.f};
    const int c = ns * 16 + c16;
    const u16* wr = bW1t + (long)c * 128 + quad * 8;
    #pragma unroll
    for (int kk = 0; kk < 4; kk++) acc = mfma16(a[kk], ld8(wr + kk * 32), acc);
    const float bias = bb1[c];
    #pragma unroll
    for (int r = 0; r < 4; r++) {
      float v = acc[r] + bias;
      H[wave * 16 + quad * 4 + r][c] = f2b(v > 0.f ? v : 0.f);
    }
  }
  __syncthreads();
  f4 acc2[8];
  #pragma unroll
  for (int ns = 0; ns < 8; ns++) acc2[ns] = (f4){0.f, 0.f, 0.f, 0.f};
  {
    s8 a2[4];
    #pragma unroll
    for (int kk = 0; kk < 4; kk++)
      a2[kk] = *reinterpret_cast<const s8*>(&H[wave * 16 + c16][kk * 32 + quad * 8]);
    #pragma unroll
    for (int ns = 0; ns < 8; ns++) {
      const u16* wr = bW2t + (long)(ns * 16 + c16) * 128 + quad * 8;
      #pragma unroll
      for (int kk = 0; kk < 4; kk++) acc2[ns] = mfma16(a2[kk], ld8(wr + kk * 32), acc2[ns]);
    }
  }
  __syncthreads();
  {
    const long bat = ((long)blockIdx.x * 64) / N_;
    const float vx0 = vxyz[bat * 3 + 0];
    const float vx1 = vxyz[bat * 3 + 1];
    const float vx2 = vxyz[bat * 3 + 2];
    for (int i = 0; i < 32; i++) {
      const int e = lane + 64 * i;
      const int rr = e >> 7, cc = e & 127;
      const long gr = row0 + rr;
      const float d0 = fabsf(pxyz[gr * 3 + 0] - vx0);
      const float d1 = fabsf(pxyz[gr * 3 + 1] - vx1);
      const float d2 = fabsf(pxyz[gr * 3 + 2] - vx2);
      float h = d0 * dW1[cc] + d1 * dW1[128 + cc] + d2 * dW1[256 + cc] + db1[cc];
      H[wave * 16 + rr][cc] = f2b(h > 0.f ? h : 0.f);
    }
  }
  __syncthreads();
  {
    s8 a2[4];
    #pragma unroll
    for (int kk = 0; kk < 4; kk++)
      a2[kk] = *reinterpret_cast<const s8*>(&H[wave * 16 + c16][kk * 32 + quad * 8]);
    #pragma unroll
    for (int ns = 0; ns < 8; ns++) {
      const u16* wr = dW2t + (long)(ns * 16 + c16) * 128 + quad * 8;
      #pragma unroll
      for (int kk = 0; kk < 4; kk++) acc2[ns] = mfma16(a2[kk], ld8(wr + kk * 32), acc2[ns]);
    }
  }
  #pragma unroll
  for (int ns = 0; ns < 8; ns++) {
    const int c = ns * 16 + c16;
    const float bias = bb2[c] + db2[c];
    #pragma unroll
    for (int r = 0; r < 4; r++)
      out[(row0 + quad * 4 + r) * D_ + c] = f2b(acc2[ns][r] + bias);
  }
}

// Pass 1: inv_colsum[b,n] = 1 / sum_m exp2(q[m]·kpv[n]*CS). Wave owns 16 n-cols.
__global__ __launch_bounds__(256) void colsum_k(const u16* __restrict__ q,
    const u16* __restrict__ kpv, float* __restrict__ inv) {
  const int tid = threadIdx.x;
  const int wave = tid >> 6, lane = tid & 63;
  const int c16 = lane & 15, quad = lane >> 4;
  const int b = blockIdx.x >> 8;
  const int nb = (blockIdx.x & 255) * 64 + wave * 16;
  s8 bk[4];
  {
    const u16* kr = kpv + ((long)b * N_ + nb + c16) * D_ + quad * 8;
    #pragma unroll
    for (int kk = 0; kk < 4; kk++) bk[kk] = ld8(kr + kk * 32);
  }
  float sum = 0.f;
  const u16* qb = q + (long)b * M_ * D_;
  for (int m0 = 0; m0 < M_; m0 += 64) {
    s8 qa[4][4];
    #pragma unroll
    for (int ms = 0; ms < 4; ms++) {
      const u16* qr = qb + (long)(m0 + ms * 16 + c16) * D_ + quad * 8;
      #pragma unroll
      for (int kk = 0; kk < 4; kk++) qa[ms][kk] = ld8(qr + kk * 32);
    }
    f4 acc[4];
    #pragma unroll
    for (int ms = 0; ms < 4; ms++) {
      acc[ms] = (f4){0.f, 0.f, 0.f, 0.f};
      #pragma unroll
      for (int kk = 0; kk < 4; kk++) acc[ms] = mfma16(qa[ms][kk], bk[kk], acc[ms]);
    }
    #pragma unroll
    for (int ms = 0; ms < 4; ms++)
      #pragma unroll
      for (int r = 0; r < 4; r++) sum += exp2f(acc[ms][r] * CS);
  }
  sum += __shfl_xor(sum, 16, 64);
  sum += __shfl_xor(sum, 32, 64);
  if (lane < 16) inv[(long)b * N_ + nb + lane] = 1.f / sum;
}

// Pass 2a (v5): partial[bid][64m][128d] over n-slice. 512 thr, dbuf P, 1 barrier/iter.
// S^T phase (r4-verified mapping): A=KPV rows n, B=Q rows m -> C col=m,row=n;
// lane's 4 regs = 4 consecutive n -> packed ds_write_b64 into P[m][n].
// PV phase: A=P rows m (LDS), B=Vt rows d.
__global__ __launch_bounds__(512, 4) void attn_v5(const u16* __restrict__ q,
    const u16* __restrict__ kpv, const u16* __restrict__ vt,
    const float* __restrict__ inv, float* __restrict__ part,
    int lgns, int nslice) {
  __shared__ u16 P[2][64][136];                  // dbuf, 2x17408 B
  const int tid = threadIdx.x;
  const int wave = tid >> 6, lane = tid & 63;
  const int c16 = lane & 15, quad = lane >> 4;
  const int bid = blockIdx.x;                    // b x mb(64) x ns
  const int ns = bid & ((1 << lgns) - 1);
  const int mb = (bid >> lgns) & 63;
  const int b = bid >> (lgns + 6);
  const int msub = wave & 3;                     // S: which 16-m (B-frag)
  const int nhalf = wave >> 2;                   // S: which 64-n half
  const int dbase = wave * 16;                   // PV: which 16-d
  const int m_base = mb * 64;
  const int n_begin = ns * nslice;

  s8 bq[4];                                      // Q as B-operand for wave's 16 m
  {
    const u16* qr = q + ((long)b * M_ + m_base + msub * 16 + c16) * D_ + quad * 8;
    #pragma unroll
    for (int kk = 0; kk < 4; kk++) bq[kk] = ld8(qr + kk * 32);
  }
  f4 acc[4];                                     // O: 4 m-tiles x wave's 16 d
  #pragma unroll
  for (int i = 0; i < 4; i++) acc[i] = (f4){0.f, 0.f, 0.f, 0.f};

  const u16* kpb = kpv + (long)b * N_ * D_;
  const u16* vtb = vt + (long)b * (long)D_ * N_;
  const float* invb = inv + (long)b * N_;

  int buf = 0;
  for (int n0 = n_begin; n0 < n_begin + nslice; n0 += 128, buf ^= 1) {
    // ---- S^T phase: 16 m (msub) x 64 n (nhalf), 4 chunks of 16 n ----
    #pragma unroll
    for (int t = 0; t < 4; t++) {
      const int n16 = nhalf * 64 + t * 16;       // n offset within 128-chunk
      const u16* kr = kpb + (long)(n0 + n16 + c16) * D_ + quad * 8;
      f4 st = {0.f, 0.f, 0.f, 0.f};
      #pragma unroll
      for (int kk = 0; kk < 4; kk++) st = mfma16(ld8(kr + kk * 32), bq[kk], st);
      const f4 ic = *reinterpret_cast<const f4*>(invb + n0 + n16 + quad * 4);
      us4 pk;
      #pragma unroll
      for (int r = 0; r < 4; r++)
        pk[r] = (u16)(__float_as_uint(exp2f(st[r] * CS) * ic[r]) >> 16);
      *reinterpret_cast<us4*>(&P[buf][msub * 16 + c16][n16 + quad * 4]) = pk;
    }
    // Vt B-frags for this 128-n chunk (independent of P; in flight over barrier)
    s8 bv[4];
    {
      const u16* vr = vtb + (long)(dbase + c16) * N_ + n0 + quad * 8;
      #pragma unroll
      for (int kk = 0; kk < 4; kk++) bv[kk] = ld8(vr + kk * 32);
    }
    __syncthreads();
    // ---- PV phase: all 64 m for wave's 16 d, K=128 ----
    #pragma unroll
    for (int i = 0; i < 4; i++) {
      #pragma unroll
      for (int kk = 0; kk < 4; kk++) {
        s8 ap = *reinterpret_cast<const s8*>(&P[buf][i * 16 + c16][kk * 32 + quad * 8]);
        acc[i] = mfma16(ap, bv[kk], acc[i]);
      }
    }
  }
  // store partial tile [64m][128d] f32; C/D: col=c16 (d), row=quad*4+r (m)
  float* pt = part + (long)bid * 64 * 128;
  #pragma unroll
  for (int i = 0; i < 4; i++)
    #pragma unroll
    for (int r = 0; r < 4; r++)
      pt[(i * 16 + quad * 4 + r) * 128 + dbase + c16] = acc[i][r];
}

// Pass 2b: out = sum_ns partial + vfeat  (f32 out)
__global__ __launch_bounds__(256) void attn_reduce(const float* __restrict__ part,
    const float* __restrict__ vfeat, float* __restrict__ out, int nsplit) {
  const int g4 = blockIdx.x * 256 + threadIdx.x;     // 0 .. B*M*D/4-1
  const int b = g4 >> 17;                            // M*D/4 = 131072
  const int rem = g4 & 131071;
  const int m = rem >> 5;
  const int d4 = rem & 31;
  const int mb = m >> 6, mr = m & 63;
  const long base = ((long)(b * 64 + mb) * nsplit) * 8192 + mr * 128 + d4 * 4;
  f4 s = *reinterpret_cast<const f4*>(vfeat + (long)g4 * 4);
  for (int ns = 0; ns < nsplit; ns++)
    s += *reinterpret_cast<const f4*>(part + base + ns * 8192);
  *reinterpret_cast<f4*>(out + (long)g4 * 4) = s;
}

extern "C" void kernel_launch(void* const* d_in, const int* in_sizes, int n_in,
                              void* d_out, int out_size, void* d_ws, size_t ws_size,
                              hipStream_t stream) {
  const float* p_xyz  = (const float*)d_in[0];
  const float* v_xyz  = (const float*)d_in[1];
  const float* p_feat = (const float*)d_in[2];
  const float* v_feat = (const float*)d_in[3];
  const float* aW1 = (const float*)d_in[4],  *ab1 = (const float*)d_in[5];
  const float* aW2 = (const float*)d_in[6],  *ab2 = (const float*)d_in[7];
  const float* bW1 = (const float*)d_in[8],  *bb1 = (const float*)d_in[9];
  const float* bW2 = (const float*)d_in[10], *bb2 = (const float*)d_in[11];
  const float* oW1 = (const float*)d_in[12], *ob1 = (const float*)d_in[13];
  const float* oW2 = (const float*)d_in[14], *ob2 = (const float*)d_in[15];
  const float* dW1 = (const float*)d_in[16], *db1 = (const float*)d_in[17];
  const float* dW2 = (const float*)d_in[18], *db2 = (const float*)d_in[19];

  char* ws = (char*)d_ws;
  u16* wt    = (u16*)ws;                               // 7 * 16384 bf16 elems
  u16* aW1t  = wt + 0 * 16384;
  u16* aW2t  = wt + 1 * 16384;
  u16* bW1t  = wt + 2 * 16384;
  u16* bW2t  = wt + 3 * 16384;
  u16* oW1t  = wt + 4 * 16384;
  u16* oW2t  = wt + 5 * 16384;
  u16* dW2t  = wt + 6 * 16384;
  u16* qbuf  = (u16*)(ws + 262144);                    // B*M*D bf16 = 2 MB
  u16* kpvb  = (u16*)(ws + 2359296);                   // B*N*D bf16 = 8 MB
  u16* vtb   = (u16*)(ws + 10747904);                  // Vt = 8 MB
  float* invb = (float*)(ws + 19136512);               // B*N f32 = 128 KB
  float* partb = (float*)(ws + 19267584);              // nsplit * 4 MB

  // nsplit: 8 if workspace allows (constant per session -> graph-safe)
  const size_t part_off = 19267584;
  int lgns = (ws_size >= part_off + (size_t)8 * B_ * M_ * D_ * 4) ? 3 : 2;
  const int nsplit = 1 << lgns;
  const int nslice = N_ / nsplit;

  wtrans<<<dim3(7), dim3(256), 0, stream>>>(aW1, aW2, bW1, bW2, oW1, oW2, dW2, wt);
  mlp2<0><<<dim3((B_ * M_) / 64), dim3(256), 0, stream>>>(v_feat, aW1t, ab1, aW2t, ab2, qbuf);
  mlp2<1><<<dim3((B_ * N_) / 64), dim3(256), 0, stream>>>(p_feat, oW1t, ob1, oW2t, ob2, vtb);
  kpv_kernel<<<dim3((B_ * N_) / 64), dim3(256), 0, stream>>>(
      p_feat, p_xyz, v_xyz, bW1t, bb1, bW2t, bb2, dW1, db1, dW2t, db2, kpvb);
  colsum_k<<<dim3(B_ * (N_ / 64)), dim3(256), 0, stream>>>(qbuf, kpvb, invb);
  attn_v5<<<dim3(B_ * 64 * nsplit), dim3(512), 0, stream>>>(qbuf, kpvb, vtb, invb, partb,
                                                            lgns, nslice);
  attn_reduce<<<dim3((B_ * M_ * D_ / 4) / 256), dim3(256), 0, stream>>>(partb, v_feat,
                                                                        (float*)d_out,
                                                                        nsplit);
}

// Round 7
// 492.149 us; speedup vs baseline: 2.2283x; 1.4398x over previous
//
#include <hip/hip_runtime.h>

#define B_ 2
#define N_ 16384
#define M_ 4096
#define D_ 128

typedef __attribute__((ext_vector_type(8))) short s8;     // 8 bf16 (4 VGPRs)
typedef __attribute__((ext_vector_type(4))) float f4;     // MFMA C/D + float4 loads
typedef __attribute__((ext_vector_type(4))) unsigned short us4;
typedef unsigned short u16;

__device__ __forceinline__ u16 f2b(float f) {   // RNE float->bf16
  unsigned int x = __float_as_uint(f);
  unsigned int r = x + 0x7fffu + ((x >> 16) & 1u);
  return (u16)(r >> 16);
}
__device__ __forceinline__ s8 ld8(const u16* p) {
  return *reinterpret_cast<const s8*>(p);
}
__device__ __forceinline__ s8 ldcvt8(const float* p) {
  f4 x = *reinterpret_cast<const f4*>(p);
  f4 y = *reinterpret_cast<const f4*>(p + 4);
  s8 r;
  r[0] = (short)f2b(x[0]); r[1] = (short)f2b(x[1]);
  r[2] = (short)f2b(x[2]); r[3] = (short)f2b(x[3]);
  r[4] = (short)f2b(y[0]); r[5] = (short)f2b(y[1]);
  r[6] = (short)f2b(y[2]); r[7] = (short)f2b(y[3]);
  return r;
}
__device__ __forceinline__ f4 mfma16(s8 a, s8 b, f4 c) {
  return __builtin_amdgcn_mfma_f32_16x16x32_bf16(a, b, c, 0, 0, 0);
}
// XOR-swizzled LDS offset for 256B rows (rows of 128 u16). off = byte offset
// in row (8B- or 16B-aligned). Same fn used by writer & reader => consistent.
__device__ __forceinline__ int swz(int row, int off) {
  return (row << 8) + ((((off >> 4) ^ (row & 15)) << 4) | (off & 15));
}
// scale * log2(e): exp(s/sqrt(128)) == exp2(s * CS)
#define CS 0.1275174365f

// Transpose seven 128x128 f32 weight matrices into ws as bf16 Wt[n][k] (B-frags).
__global__ void wtrans(const float* a0, const float* a1, const float* a2, const float* a3,
                       const float* a4, const float* a5, const float* a6, u16* dst) {
  const float* s;
  switch (blockIdx.x) {
    case 0: s = a0; break; case 1: s = a1; break; case 2: s = a2; break;
    case 3: s = a3; break; case 4: s = a4; break; case 5: s = a5; break;
    default: s = a6; break;
  }
  u16* d = dst + blockIdx.x * 16384;
  for (int i = threadIdx.x; i < 16384; i += 256) {
    int r = i >> 7, c = i & 127;
    d[c * 128 + r] = f2b(s[i]);
  }
}

// Fused 2-layer MLP: out = relu(X@W1+b1)@W2+b2 (X f32, out bf16 in ws).
template<int TRANSOUT>
__global__ __launch_bounds__(256) void mlp2(const float* __restrict__ X,
    const u16* __restrict__ W1t, const float* __restrict__ b1,
    const u16* __restrict__ W2t, const float* __restrict__ b2,
    u16* __restrict__ out) {
  __shared__ u16 H[64][136];
  const int tid = threadIdx.x;
  const int wave = tid >> 6, lane = tid & 63;
  const int c16 = lane & 15, quad = lane >> 4;
  const long row0 = (long)blockIdx.x * 64 + wave * 16;

  s8 a[4];
  {
    const float* xr = X + (row0 + c16) * D_ + quad * 8;
    #pragma unroll
    for (int kk = 0; kk < 4; kk++) a[kk] = ldcvt8(xr + kk * 32);
  }
  #pragma unroll
  for (int ns = 0; ns < 8; ns++) {
    f4 acc = {0.f, 0.f, 0.f, 0.f};
    const int c = ns * 16 + c16;
    const u16* wr = W1t + (long)c * 128 + quad * 8;
    #pragma unroll
    for (int kk = 0; kk < 4; kk++) acc = mfma16(a[kk], ld8(wr + kk * 32), acc);
    const float bias = b1[c];
    #pragma unroll
    for (int r = 0; r < 4; r++) {
      float v = acc[r] + bias;
      H[wave * 16 + quad * 4 + r][c] = f2b(v > 0.f ? v : 0.f);
    }
  }
  __syncthreads();
  s8 a2[4];
  #pragma unroll
  for (int kk = 0; kk < 4; kk++)
    a2[kk] = *reinterpret_cast<const s8*>(&H[wave * 16 + c16][kk * 32 + quad * 8]);
  #pragma unroll
  for (int ns = 0; ns < 8; ns++) {
    f4 acc = {0.f, 0.f, 0.f, 0.f};
    const int c = ns * 16 + c16;
    const u16* wr = W2t + (long)c * 128 + quad * 8;
    #pragma unroll
    for (int kk = 0; kk < 4; kk++) acc = mfma16(a2[kk], ld8(wr + kk * 32), acc);
    const float bias = b2[c];
    if (TRANSOUT == 0) {
      #pragma unroll
      for (int r = 0; r < 4; r++)
        out[(row0 + quad * 4 + r) * D_ + c] = f2b(acc[r] + bias);
    } else {
      const long g = row0 + quad * 4;
      const long bb = g >> 14;
      const long n = g & (N_ - 1);
      us4 pk;
      #pragma unroll
      for (int r = 0; r < 4; r++) pk[r] = f2b(acc[r] + bias);
      *reinterpret_cast<us4*>(out + bb * (long)128 * N_ + (long)c * N_ + n) = pk;
    }
  }
}

// kpv = relu(p_feat@bW1+bb1)@bW2 + relu(|p_xyz-v_xyz|@dW1+db1)@dW2 + (bb2+db2)
__global__ __launch_bounds__(256) void kpv_kernel(
    const float* __restrict__ pf, const float* __restrict__ pxyz, const float* __restrict__ vxyz,
    const u16* __restrict__ bW1t, const float* __restrict__ bb1,
    const u16* __restrict__ bW2t, const float* __restrict__ bb2,
    const float* __restrict__ dW1, const float* __restrict__ db1,
    const u16* __restrict__ dW2t, const float* __restrict__ db2,
    u16* __restrict__ out) {
  __shared__ u16 H[64][136];
  const int tid = threadIdx.x;
  const int wave = tid >> 6, lane = tid & 63;
  const int c16 = lane & 15, quad = lane >> 4;
  const long row0 = (long)blockIdx.x * 64 + wave * 16;

  s8 a[4];
  {
    const float* xr = pf + (row0 + c16) * D_ + quad * 8;
    #pragma unroll
    for (int kk = 0; kk < 4; kk++) a[kk] = ldcvt8(xr + kk * 32);
  }
  #pragma unroll
  for (int ns = 0; ns < 8; ns++) {
    f4 acc = {0.f, 0.f, 0.f, 0.f};
    const int c = ns * 16 + c16;
    const u16* wr = bW1t + (long)c * 128 + quad * 8;
    #pragma unroll
    for (int kk = 0; kk < 4; kk++) acc = mfma16(a[kk], ld8(wr + kk * 32), acc);
    const float bias = bb1[c];
    #pragma unroll
    for (int r = 0; r < 4; r++) {
      float v = acc[r] + bias;
      H[wave * 16 + quad * 4 + r][c] = f2b(v > 0.f ? v : 0.f);
    }
  }
  __syncthreads();
  f4 acc2[8];
  #pragma unroll
  for (int ns = 0; ns < 8; ns++) acc2[ns] = (f4){0.f, 0.f, 0.f, 0.f};
  {
    s8 a2[4];
    #pragma unroll
    for (int kk = 0; kk < 4; kk++)
      a2[kk] = *reinterpret_cast<const s8*>(&H[wave * 16 + c16][kk * 32 + quad * 8]);
    #pragma unroll
    for (int ns = 0; ns < 8; ns++) {
      const u16* wr = bW2t + (long)(ns * 16 + c16) * 128 + quad * 8;
      #pragma unroll
      for (int kk = 0; kk < 4; kk++) acc2[ns] = mfma16(a2[kk], ld8(wr + kk * 32), acc2[ns]);
    }
  }
  __syncthreads();
  {
    const long bat = ((long)blockIdx.x * 64) / N_;
    const float vx0 = vxyz[bat * 3 + 0];
    const float vx1 = vxyz[bat * 3 + 1];
    const float vx2 = vxyz[bat * 3 + 2];
    for (int i = 0; i < 32; i++) {
      const int e = lane + 64 * i;
      const int rr = e >> 7, cc = e & 127;
      const long gr = row0 + rr;
      const float d0 = fabsf(pxyz[gr * 3 + 0] - vx0);
      const float d1 = fabsf(pxyz[gr * 3 + 1] - vx1);
      const float d2 = fabsf(pxyz[gr * 3 + 2] - vx2);
      float h = d0 * dW1[cc] + d1 * dW1[128 + cc] + d2 * dW1[256 + cc] + db1[cc];
      H[wave * 16 + rr][cc] = f2b(h > 0.f ? h : 0.f);
    }
  }
  __syncthreads();
  {
    s8 a2[4];
    #pragma unroll
    for (int kk = 0; kk < 4; kk++)
      a2[kk] = *reinterpret_cast<const s8*>(&H[wave * 16 + c16][kk * 32 + quad * 8]);
    #pragma unroll
    for (int ns = 0; ns < 8; ns++) {
      const u16* wr = dW2t + (long)(ns * 16 + c16) * 128 + quad * 8;
      #pragma unroll
      for (int kk = 0; kk < 4; kk++) acc2[ns] = mfma16(a2[kk], ld8(wr + kk * 32), acc2[ns]);
    }
  }
  #pragma unroll
  for (int ns = 0; ns < 8; ns++) {
    const int c = ns * 16 + c16;
    const float bias = bb2[c] + db2[c];
    #pragma unroll
    for (int r = 0; r < 4; r++)
      out[(row0 + quad * 4 + r) * D_ + c] = f2b(acc2[ns][r] + bias);
  }
}

// Pass 1 v2: block owns 128 n (wave w: 16 n, KPV A-frags in regs). Loop m in
// 64-chunks: stage Q chunk in LDS (shared by all 8 waves), S^T via
// mfma16(kpv, q) (C: col=m, row=n), exp2 accumulate, cross-lane reduce at end.
__global__ __launch_bounds__(512, 6) void colsum_v2(const u16* __restrict__ q,
    const u16* __restrict__ kpv, float* __restrict__ inv) {
  __shared__ char LQ[16384];                     // 64 m x 128 k bf16, swizzled
  const int tid = threadIdx.x;
  const int wave = tid >> 6, lane = tid & 63;
  const int c16 = lane & 15, quad = lane >> 4;
  const int b = blockIdx.x >> 7;                 // 128 blocks per batch
  const int nb = (blockIdx.x & 127) * 128 + wave * 16;
  const int rsub = lane >> 4, ch = lane & 15;    // staging roles

  s8 ak[4];                                      // KPV A-frag: rows n = nb+c16
  {
    const u16* kr = kpv + ((long)b * N_ + nb + c16) * D_ + quad * 8;
    #pragma unroll
    for (int kk = 0; kk < 4; kk++) ak[kk] = ld8(kr + kk * 32);
  }
  f4 sum = {0.f, 0.f, 0.f, 0.f};
  const u16* qb = q + (long)b * M_ * D_;

  for (int m0 = 0; m0 < M_; m0 += 64) {
    // stage Q rows m0..m0+63 (wave stages 8 rows; 2 insts of 4 rows)
    s8 t0 = ld8(qb + (long)(m0 + wave * 8 + rsub) * D_ + ch * 8);
    s8 t1 = ld8(qb + (long)(m0 + wave * 8 + 4 + rsub) * D_ + ch * 8);
    *reinterpret_cast<s8*>(LQ + swz(wave * 8 + rsub, ch * 16)) = t0;
    *reinterpret_cast<s8*>(LQ + swz(wave * 8 + 4 + rsub, ch * 16)) = t1;
    __syncthreads();
    #pragma unroll
    for (int ms = 0; ms < 4; ms++) {
      f4 st = {0.f, 0.f, 0.f, 0.f};
      #pragma unroll
      for (int kk = 0; kk < 4; kk++) {
        s8 bq = *reinterpret_cast<const s8*>(LQ + swz(ms * 16 + c16, kk * 64 + quad * 16));
        st = mfma16(ak[kk], bq, st);
      }
      #pragma unroll
      for (int r = 0; r < 4; r++) sum[r] += exp2f(st[r] * CS);
    }
    __syncthreads();                             // WAR: Q reads vs next stage
  }
  // reduce over the 16 m-lanes (c16)
  #pragma unroll
  for (int mask = 1; mask < 16; mask <<= 1) {
    #pragma unroll
    for (int r = 0; r < 4; r++) sum[r] += __shfl_xor(sum[r], mask, 64);
  }
  if (c16 == 0) {
    f4 iv;
    #pragma unroll
    for (int r = 0; r < 4; r++) iv[r] = 1.f / sum[r];
    *reinterpret_cast<f4*>(inv + (long)b * N_ + nb + quad * 4) = iv;
  }
}

// Pass 2a v6: per 128-n iter stage KPV chunk in LDS (once, shared by all
// waves - kills the 4x msub redundancy that made v5 L1-bound). S^T phase
// reads A=KPV from LDS, writes P to LDS (swizzled); PV reads P + direct Vt.
__global__ __launch_bounds__(512, 6) void attn_v6(const u16* __restrict__ q,
    const u16* __restrict__ kpv, const u16* __restrict__ vt,
    const float* __restrict__ inv, float* __restrict__ part,
    int lgns, int nslice) {
  __shared__ char LK[32768];                     // 128 n x 128 d bf16, swizzled
  __shared__ char LP[16384];                     // 64 m x 128 n bf16, swizzled
  const int tid = threadIdx.x;
  const int wave = tid >> 6, lane = tid & 63;
  const int c16 = lane & 15, quad = lane >> 4;
  const int bid = blockIdx.x;                    // b x mb(64) x ns
  const int ns = bid & ((1 << lgns) - 1);
  const int mb = (bid >> lgns) & 63;
  const int b = bid >> (lgns + 6);
  const int msub = wave & 3;                     // S: which 16-m
  const int nhalf = wave >> 2;                   // S: which 64-n half
  const int dbase = wave * 16;                   // PV: which 16-d
  const int m_base = mb * 64;
  const int n_begin = ns * nslice;
  const int rsub = lane >> 4, ch = lane & 15;    // staging roles

  s8 bq[4];                                      // Q B-frag for wave's 16 m
  {
    const u16* qr = q + ((long)b * M_ + m_base + msub * 16 + c16) * D_ + quad * 8;
    #pragma unroll
    for (int kk = 0; kk < 4; kk++) bq[kk] = ld8(qr + kk * 32);
  }
  f4 acc[4];                                     // O: 4 m-tiles x wave's 16 d
  #pragma unroll
  for (int i = 0; i < 4; i++) acc[i] = (f4){0.f, 0.f, 0.f, 0.f};

  const u16* kpb = kpv + (long)b * N_ * D_;
  const u16* vtb = vt + (long)b * (long)D_ * N_;
  const float* invb = inv + (long)b * N_;

  for (int n0 = n_begin; n0 < n_begin + nslice; n0 += 128) {
    // ---- stage KPV chunk [128n][128d] -> LK (wave stages 16 rows) ----
    s8 tmp[4];
    #pragma unroll
    for (int i = 0; i < 4; i++)
      tmp[i] = ld8(kpb + (long)(n0 + wave * 16 + i * 4 + rsub) * D_ + ch * 8);
    // Vt B-frags (per-wave unique, direct; in flight across barrier)
    s8 bv[4];
    {
      const u16* vr = vtb + (long)(dbase + c16) * N_ + n0 + quad * 8;
      #pragma unroll
      for (int kk = 0; kk < 4; kk++) bv[kk] = ld8(vr + kk * 32);
    }
    #pragma unroll
    for (int i = 0; i < 4; i++)
      *reinterpret_cast<s8*>(LK + swz(wave * 16 + i * 4 + rsub, ch * 16)) = tmp[i];
    __syncthreads();                             // stage done -> S reads
    // ---- S^T phase: 16 m (msub) x 64 n (nhalf) ----
    #pragma unroll
    for (int t = 0; t < 4; t++) {
      const int n16 = nhalf * 64 + t * 16;
      f4 st = {0.f, 0.f, 0.f, 0.f};
      #pragma unroll
      for (int kk = 0; kk < 4; kk++) {
        s8 aK = *reinterpret_cast<const s8*>(LK + swz(n16 + c16, kk * 64 + quad * 16));
        st = mfma16(aK, bq[kk], st);
      }
      const f4 ic = *reinterpret_cast<const f4*>(invb + n0 + n16 + quad * 4);
      us4 pk;
      #pragma unroll
      for (int r = 0; r < 4; r++)
        pk[r] = (u16)(__float_as_uint(exp2f(st[r] * CS) * ic[r]) >> 16);
      *reinterpret_cast<us4*>(LP + swz(msub * 16 + c16, n16 * 2 + quad * 8)) = pk;
    }
    __syncthreads();                             // S done -> PV reads / next stage
    // ---- PV phase: all 64 m for wave's 16 d, K=128 ----
    #pragma unroll
    for (int i = 0; i < 4; i++) {
      #pragma unroll
      for (int kk = 0; kk < 4; kk++) {
        s8 ap = *reinterpret_cast<const s8*>(LP + swz(i * 16 + c16, kk * 64 + quad * 16));
        acc[i] = mfma16(ap, bv[kk], acc[i]);
      }
    }
  }
  // store partial tile [64m][128d] f32; C/D: col=c16 (d), row=quad*4+r (m)
  float* pt = part + (long)bid * 64 * 128;
  #pragma unroll
  for (int i = 0; i < 4; i++)
    #pragma unroll
    for (int r = 0; r < 4; r++)
      pt[(i * 16 + quad * 4 + r) * 128 + dbase + c16] = acc[i][r];
}

// Pass 2b: out = sum_ns partial + vfeat  (f32 out)
__global__ __launch_bounds__(256) void attn_reduce(const float* __restrict__ part,
    const float* __restrict__ vfeat, float* __restrict__ out, int nsplit) {
  const int g4 = blockIdx.x * 256 + threadIdx.x;     // 0 .. B*M*D/4-1
  const int b = g4 >> 17;                            // M*D/4 = 131072
  const int rem = g4 & 131071;
  const int m = rem >> 5;
  const int d4 = rem & 31;
  const int mb = m >> 6, mr = m & 63;
  const long base = ((long)(b * 64 + mb) * nsplit) * 8192 + mr * 128 + d4 * 4;
  f4 s = *reinterpret_cast<const f4*>(vfeat + (long)g4 * 4);
  for (int ns = 0; ns < nsplit; ns++)
    s += *reinterpret_cast<const f4*>(part + base + ns * 8192);
  *reinterpret_cast<f4*>(out + (long)g4 * 4) = s;
}

extern "C" void kernel_launch(void* const* d_in, const int* in_sizes, int n_in,
                              void* d_out, int out_size, void* d_ws, size_t ws_size,
                              hipStream_t stream) {
  const float* p_xyz  = (const float*)d_in[0];
  const float* v_xyz  = (const float*)d_in[1];
  const float* p_feat = (const float*)d_in[2];
  const float* v_feat = (const float*)d_in[3];
  const float* aW1 = (const float*)d_in[4],  *ab1 = (const float*)d_in[5];
  const float* aW2 = (const float*)d_in[6],  *ab2 = (const float*)d_in[7];
  const float* bW1 = (const float*)d_in[8],  *bb1 = (const float*)d_in[9];
  const float* bW2 = (const float*)d_in[10], *bb2 = (const float*)d_in[11];
  const float* oW1 = (const float*)d_in[12], *ob1 = (const float*)d_in[13];
  const float* oW2 = (const float*)d_in[14], *ob2 = (const float*)d_in[15];
  const float* dW1 = (const float*)d_in[16], *db1 = (const float*)d_in[17];
  const float* dW2 = (const float*)d_in[18], *db2 = (const float*)d_in[19];

  char* ws = (char*)d_ws;
  u16* wt    = (u16*)ws;                               // 7 * 16384 bf16 elems
  u16* aW1t  = wt + 0 * 16384;
  u16* aW2t  = wt + 1 * 16384;
  u16* bW1t  = wt + 2 * 16384;
  u16* bW2t  = wt + 3 * 16384;
  u16* oW1t  = wt + 4 * 16384;
  u16* oW2t  = wt + 5 * 16384;
  u16* dW2t  = wt + 6 * 16384;
  u16* qbuf  = (u16*)(ws + 262144);                    // B*M*D bf16 = 2 MB
  u16* kpvb  = (u16*)(ws + 2359296);                   // B*N*D bf16 = 8 MB
  u16* vtb   = (u16*)(ws + 10747904);                  // Vt = 8 MB
  float* invb = (float*)(ws + 19136512);               // B*N f32 = 128 KB
  float* partb = (float*)(ws + 19267584);              // nsplit * 4 MB

  const size_t part_off = 19267584;
  int lgns = (ws_size >= part_off + (size_t)8 * B_ * M_ * D_ * 4) ? 3 : 2;
  const int nsplit = 1 << lgns;
  const int nslice = N_ / nsplit;

  wtrans<<<dim3(7), dim3(256), 0, stream>>>(aW1, aW2, bW1, bW2, oW1, oW2, dW2, wt);
  mlp2<0><<<dim3((B_ * M_) / 64), dim3(256), 0, stream>>>(v_feat, aW1t, ab1, aW2t, ab2, qbuf);
  mlp2<1><<<dim3((B_ * N_) / 64), dim3(256), 0, stream>>>(p_feat, oW1t, ob1, oW2t, ob2, vtb);
  kpv_kernel<<<dim3((B_ * N_) / 64), dim3(256), 0, stream>>>(
      p_feat, p_xyz, v_xyz, bW1t, bb1, bW2t, bb2, dW1, db1, dW2t, db2, kpvb);
  colsum_v2<<<dim3(B_ * (N_ / 128)), dim3(512), 0, stream>>>(qbuf, kpvb, invb);
  attn_v6<<<dim3(B_ * 64 * nsplit), dim3(512), 0, stream>>>(qbuf, kpvb, vtb, invb, partb,
                                                            lgns, nslice);
  attn_reduce<<<dim3((B_ * M_ * D_ / 4) / 256), dim3(256), 0, stream>>>(partb, v_feat,
                                                                        (float*)d_out,
                                                                        nsplit);
}

// Round 8
// 394.889 us; speedup vs baseline: 2.7772x; 1.2463x over previous
//
#include <hip/hip_runtime.h>

#define B_ 2
#define N_ 16384
#define M_ 4096
#define D_ 128

typedef __attribute__((ext_vector_type(8))) short s8;     // 8 bf16 (4 VGPRs)
typedef __attribute__((ext_vector_type(4))) float f4;     // MFMA C/D + float4 loads
typedef __attribute__((ext_vector_type(16))) float f16v;  // 32x32 MFMA C/D
typedef __attribute__((ext_vector_type(4))) unsigned short us4;
typedef unsigned short u16;

__device__ __forceinline__ u16 f2b(float f) {   // RNE float->bf16
  unsigned int x = __float_as_uint(f);
  unsigned int r = x + 0x7fffu + ((x >> 16) & 1u);
  return (u16)(r >> 16);
}
__device__ __forceinline__ s8 ld8(const u16* p) {
  return *reinterpret_cast<const s8*>(p);
}
__device__ __forceinline__ s8 ldcvt8(const float* p) {
  f4 x = *reinterpret_cast<const f4*>(p);
  f4 y = *reinterpret_cast<const f4*>(p + 4);
  s8 r;
  r[0] = (short)f2b(x[0]); r[1] = (short)f2b(x[1]);
  r[2] = (short)f2b(x[2]); r[3] = (short)f2b(x[3]);
  r[4] = (short)f2b(y[0]); r[5] = (short)f2b(y[1]);
  r[6] = (short)f2b(y[2]); r[7] = (short)f2b(y[3]);
  return r;
}
__device__ __forceinline__ f4 mfma16(s8 a, s8 b, f4 c) {
  return __builtin_amdgcn_mfma_f32_16x16x32_bf16(a, b, c, 0, 0, 0);
}
__device__ __forceinline__ f16v mfma32(s8 a, s8 b, f16v c) {
  return __builtin_amdgcn_mfma_f32_32x32x16_bf16(a, b, c, 0, 0, 0);
}
// XOR-swizzled LDS offset for 256B rows. off = byte offset in row (16B units).
__device__ __forceinline__ int swz(int row, int off) {
  return (row << 8) + ((((off >> 4) ^ (row & 15)) << 4) | (off & 15));
}
// scale * log2(e): exp(s/sqrt(128)) == exp2(s * CS)
#define CS 0.1275174365f

// Transpose seven 128x128 f32 weight matrices into ws as bf16 Wt[n][k] (B-frags).
__global__ void wtrans(const float* a0, const float* a1, const float* a2, const float* a3,
                       const float* a4, const float* a5, const float* a6, u16* dst) {
  const float* s;
  switch (blockIdx.x) {
    case 0: s = a0; break; case 1: s = a1; break; case 2: s = a2; break;
    case 3: s = a3; break; case 4: s = a4; break; case 5: s = a5; break;
    default: s = a6; break;
  }
  u16* d = dst + blockIdx.x * 16384;
  for (int i = threadIdx.x; i < 16384; i += 256) {
    int r = i >> 7, c = i & 127;
    d[c * 128 + r] = f2b(s[i]);
  }
}

// Fused 2-layer MLP: out = relu(X@W1+b1)@W2+b2 (X f32, out bf16 in ws).
template<int TRANSOUT>
__global__ __launch_bounds__(256) void mlp2(const float* __restrict__ X,
    const u16* __restrict__ W1t, const float* __restrict__ b1,
    const u16* __restrict__ W2t, const float* __restrict__ b2,
    u16* __restrict__ out) {
  __shared__ u16 H[64][136];
  const int tid = threadIdx.x;
  const int wave = tid >> 6, lane = tid & 63;
  const int c16 = lane & 15, quad = lane >> 4;
  const long row0 = (long)blockIdx.x * 64 + wave * 16;

  s8 a[4];
  {
    const float* xr = X + (row0 + c16) * D_ + quad * 8;
    #pragma unroll
    for (int kk = 0; kk < 4; kk++) a[kk] = ldcvt8(xr + kk * 32);
  }
  #pragma unroll
  for (int ns = 0; ns < 8; ns++) {
    f4 acc = {0.f, 0.f, 0.f, 0.f};
    const int c = ns * 16 + c16;
    const u16* wr = W1t + (long)c * 128 + quad * 8;
    #pragma unroll
    for (int kk = 0; kk < 4; kk++) acc = mfma16(a[kk], ld8(wr + kk * 32), acc);
    const float bias = b1[c];
    #pragma unroll
    for (int r = 0; r < 4; r++) {
      float v = acc[r] + bias;
      H[wave * 16 + quad * 4 + r][c] = f2b(v > 0.f ? v : 0.f);
    }
  }
  __syncthreads();
  s8 a2[4];
  #pragma unroll
  for (int kk = 0; kk < 4; kk++)
    a2[kk] = *reinterpret_cast<const s8*>(&H[wave * 16 + c16][kk * 32 + quad * 8]);
  #pragma unroll
  for (int ns = 0; ns < 8; ns++) {
    f4 acc = {0.f, 0.f, 0.f, 0.f};
    const int c = ns * 16 + c16;
    const u16* wr = W2t + (long)c * 128 + quad * 8;
    #pragma unroll
    for (int kk = 0; kk < 4; kk++) acc = mfma16(a2[kk], ld8(wr + kk * 32), acc);
    const float bias = b2[c];
    if (TRANSOUT == 0) {
      #pragma unroll
      for (int r = 0; r < 4; r++)
        out[(row0 + quad * 4 + r) * D_ + c] = f2b(acc[r] + bias);
    } else {
      const long g = row0 + quad * 4;
      const long bb = g >> 14;
      const long n = g & (N_ - 1);
      us4 pk;
      #pragma unroll
      for (int r = 0; r < 4; r++) pk[r] = f2b(acc[r] + bias);
      *reinterpret_cast<us4*>(out + bb * (long)128 * N_ + (long)c * N_ + n) = pk;
    }
  }
}

// kpv = relu(p_feat@bW1+bb1)@bW2 + relu(|p_xyz-v_xyz|@dW1+db1)@dW2 + (bb2+db2)
__global__ __launch_bounds__(256) void kpv_kernel(
    const float* __restrict__ pf, const float* __restrict__ pxyz, const float* __restrict__ vxyz,
    const u16* __restrict__ bW1t, const float* __restrict__ bb1,
    const u16* __restrict__ bW2t, const float* __restrict__ bb2,
    const float* __restrict__ dW1, const float* __restrict__ db1,
    const u16* __restrict__ dW2t, const float* __restrict__ db2,
    u16* __restrict__ out) {
  __shared__ u16 H[64][136];
  const int tid = threadIdx.x;
  const int wave = tid >> 6, lane = tid & 63;
  const int c16 = lane & 15, quad = lane >> 4;
  const long row0 = (long)blockIdx.x * 64 + wave * 16;

  s8 a[4];
  {
    const float* xr = pf + (row0 + c16) * D_ + quad * 8;
    #pragma unroll
    for (int kk = 0; kk < 4; kk++) a[kk] = ldcvt8(xr + kk * 32);
  }
  #pragma unroll
  for (int ns = 0; ns < 8; ns++) {
    f4 acc = {0.f, 0.f, 0.f, 0.f};
    const int c = ns * 16 + c16;
    const u16* wr = bW1t + (long)c * 128 + quad * 8;
    #pragma unroll
    for (int kk = 0; kk < 4; kk++) acc = mfma16(a[kk], ld8(wr + kk * 32), acc);
    const float bias = bb1[c];
    #pragma unroll
    for (int r = 0; r < 4; r++) {
      float v = acc[r] + bias;
      H[wave * 16 + quad * 4 + r][c] = f2b(v > 0.f ? v : 0.f);
    }
  }
  __syncthreads();
  f4 acc2[8];
  #pragma unroll
  for (int ns = 0; ns < 8; ns++) acc2[ns] = (f4){0.f, 0.f, 0.f, 0.f};
  {
    s8 a2[4];
    #pragma unroll
    for (int kk = 0; kk < 4; kk++)
      a2[kk] = *reinterpret_cast<const s8*>(&H[wave * 16 + c16][kk * 32 + quad * 8]);
    #pragma unroll
    for (int ns = 0; ns < 8; ns++) {
      const u16* wr = bW2t + (long)(ns * 16 + c16) * 128 + quad * 8;
      #pragma unroll
      for (int kk = 0; kk < 4; kk++) acc2[ns] = mfma16(a2[kk], ld8(wr + kk * 32), acc2[ns]);
    }
  }
  __syncthreads();
  {
    const long bat = ((long)blockIdx.x * 64) / N_;
    const float vx0 = vxyz[bat * 3 + 0];
    const float vx1 = vxyz[bat * 3 + 1];
    const float vx2 = vxyz[bat * 3 + 2];
    for (int i = 0; i < 32; i++) {
      const int e = lane + 64 * i;
      const int rr = e >> 7, cc = e & 127;
      const long gr = row0 + rr;
      const float d0 = fabsf(pxyz[gr * 3 + 0] - vx0);
      const float d1 = fabsf(pxyz[gr * 3 + 1] - vx1);
      const float d2 = fabsf(pxyz[gr * 3 + 2] - vx2);
      float h = d0 * dW1[cc] + d1 * dW1[128 + cc] + d2 * dW1[256 + cc] + db1[cc];
      H[wave * 16 + rr][cc] = f2b(h > 0.f ? h : 0.f);
    }
  }
  __syncthreads();
  {
    s8 a2[4];
    #pragma unroll
    for (int kk = 0; kk < 4; kk++)
      a2[kk] = *reinterpret_cast<const s8*>(&H[wave * 16 + c16][kk * 32 + quad * 8]);
    #pragma unroll
    for (int ns = 0; ns < 8; ns++) {
      const u16* wr = dW2t + (long)(ns * 16 + c16) * 128 + quad * 8;
      #pragma unroll
      for (int kk = 0; kk < 4; kk++) acc2[ns] = mfma16(a2[kk], ld8(wr + kk * 32), acc2[ns]);
    }
  }
  #pragma unroll
  for (int ns = 0; ns < 8; ns++) {
    const int c = ns * 16 + c16;
    const float bias = bb2[c] + db2[c];
    #pragma unroll
    for (int r = 0; r < 4; r++)
      out[(row0 + quad * 4 + r) * D_ + c] = f2b(acc2[ns][r] + bias);
  }
}

// Pass 1 v2: block owns 128 n; stage Q chunks in LDS, S^T via mfma16(kpv,q).
__global__ __launch_bounds__(512, 6) void colsum_v2(const u16* __restrict__ q,
    const u16* __restrict__ kpv, float* __restrict__ inv) {
  __shared__ char LQ[16384];                     // 64 m x 128 k bf16, swizzled
  const int tid = threadIdx.x;
  const int wave = tid >> 6, lane = tid & 63;
  const int c16 = lane & 15, quad = lane >> 4;
  const int b = blockIdx.x >> 7;
  const int nb = (blockIdx.x & 127) * 128 + wave * 16;
  const int rsub = lane >> 4, ch = lane & 15;

  s8 ak[4];
  {
    const u16* kr = kpv + ((long)b * N_ + nb + c16) * D_ + quad * 8;
    #pragma unroll
    for (int kk = 0; kk < 4; kk++) ak[kk] = ld8(kr + kk * 32);
  }
  f4 sum = {0.f, 0.f, 0.f, 0.f};
  const u16* qb = q + (long)b * M_ * D_;

  for (int m0 = 0; m0 < M_; m0 += 64) {
    s8 t0 = ld8(qb + (long)(m0 + wave * 8 + rsub) * D_ + ch * 8);
    s8 t1 = ld8(qb + (long)(m0 + wave * 8 + 4 + rsub) * D_ + ch * 8);
    *reinterpret_cast<s8*>(LQ + swz(wave * 8 + rsub, ch * 16)) = t0;
    *reinterpret_cast<s8*>(LQ + swz(wave * 8 + 4 + rsub, ch * 16)) = t1;
    __syncthreads();
    #pragma unroll
    for (int ms = 0; ms < 4; ms++) {
      f4 st = {0.f, 0.f, 0.f, 0.f};
      #pragma unroll
      for (int kk = 0; kk < 4; kk++) {
        s8 bq = *reinterpret_cast<const s8*>(LQ + swz(ms * 16 + c16, kk * 64 + quad * 16));
        st = mfma16(ak[kk], bq, st);
      }
      #pragma unroll
      for (int r = 0; r < 4; r++) sum[r] += exp2f(st[r] * CS);
    }
    __syncthreads();
  }
  #pragma unroll
  for (int mask = 1; mask < 16; mask <<= 1) {
    #pragma unroll
    for (int r = 0; r < 4; r++) sum[r] += __shfl_xor(sum[r], mask, 64);
  }
  if (c16 == 0) {
    f4 iv;
    #pragma unroll
    for (int r = 0; r < 4; r++) iv[r] = 1.f / sum[r];
    *reinterpret_cast<f4*>(inv + (long)b * N_ + nb + quad * 4) = iv;
  }
}

// Pass 2a v7: 256 thr (4 waves), 64m x 128d tile, 64-n chunks, 32x32x16 MFMA.
// LK: KPV chunk [64n][128d] swizzled (16 KB). LP: P in A-frag order (8 KB):
//   element (m, n) at granule (n>>3)*1024 + m*16 + (n&7)*2.
// S^T: A=KPV(LK), B=Q(regs) -> C col=m,row=n -> exp2*inv -> LP.
// PV: A=P(LP, linear reads), B=Vt(global) -> C col=d,row=m.
// Register prefetch of next KPV chunk hides global latency across S+PV.
__global__ __launch_bounds__(256, 4) void attn_v7(const u16* __restrict__ q,
    const u16* __restrict__ kpv, const u16* __restrict__ vt,
    const float* __restrict__ inv, float* __restrict__ part,
    int lgns, int nslice) {
  __shared__ char LK[16384];
  __shared__ char LP[8192];
  const int tid = threadIdx.x;
  const int wave = tid >> 6, lane = tid & 63;
  const int l31 = lane & 31, hi = lane >> 5;
  const int bid = blockIdx.x;                    // b x mb(64) x ns
  const int ns = bid & ((1 << lgns) - 1);
  const int mb = (bid >> lgns) & 63;
  const int b = bid >> (lgns + 6);
  const int nt = wave & 1, mt = wave >> 1;       // S^T tile: 32n x 32m
  const int m_base = mb * 64;
  const int n_begin = ns * nslice;
  const int rsub = lane >> 4, ch = lane & 15;    // staging roles

  const u16* kpb = kpv + (long)b * N_ * D_;
  const u16* vtb = vt + (long)b * (long)D_ * N_;
  const float* invb = inv + (long)b * N_;

  s8 bq[8];                                      // Q B-frags: 8 ksteps (K=128)
  {
    const u16* qr = q + ((long)b * M_ + m_base + mt * 32 + l31) * D_ + hi * 8;
    #pragma unroll
    for (int kk = 0; kk < 8; kk++) bq[kk] = ld8(qr + kk * 16);
  }
  f16v acc[2];                                   // O: 2 m-tiles x wave's 32 d
  #pragma unroll
  for (int i = 0; i < 2; i++)
    #pragma unroll
    for (int r = 0; r < 16; r++) acc[i][r] = 0.f;

  // preload first KPV chunk into regs
  s8 tmp[4];
  #pragma unroll
  for (int i = 0; i < 4; i++)
    tmp[i] = ld8(kpb + (long)(n_begin + wave * 16 + i * 4 + rsub) * D_ + ch * 8);

  for (int n0 = n_begin; n0 < n_begin + nslice; n0 += 64) {
    // write staged KPV(i) -> LK
    #pragma unroll
    for (int i = 0; i < 4; i++)
      *reinterpret_cast<s8*>(LK + swz(wave * 16 + i * 4 + rsub, ch * 16)) = tmp[i];
    // prefetch KPV(i+1)
    {
      int nn = n0 + 64;
      if (nn >= n_begin + nslice) nn = n_begin;  // last iter: dummy (unused)
      #pragma unroll
      for (int i = 0; i < 4; i++)
        tmp[i] = ld8(kpb + (long)(nn + wave * 16 + i * 4 + rsub) * D_ + ch * 8);
    }
    __syncthreads();                             // LK ready; LP safe (PV(i-1) done)
    // ---- S^T: wave tile 32n(nt) x 32m(mt), K=128 ----
    {
      f16v st;
      #pragma unroll
      for (int r = 0; r < 16; r++) st[r] = 0.f;
      #pragma unroll
      for (int kk = 0; kk < 8; kk++) {
        s8 aK = *reinterpret_cast<const s8*>(
            LK + swz(nt * 32 + l31, kk * 32 + hi * 16));
        st = mfma32(aK, bq[kk], st);
      }
      // C: col=m (l31), row n = nt*32 + 8g + 4hi + r  (reg = g*4+r)
      #pragma unroll
      for (int g = 0; g < 4; g++) {
        const f4 ic = *reinterpret_cast<const f4*>(invb + n0 + nt * 32 + 8 * g + 4 * hi);
        us4 pk;
        #pragma unroll
        for (int r = 0; r < 4; r++)
          pk[r] = (u16)(__float_as_uint(exp2f(st[g * 4 + r] * CS) * ic[r]) >> 16);
        // LP: granule (4nt+g), row m = mt*32+l31, byte 8*hi
        *reinterpret_cast<us4*>(LP + (4 * nt + g) * 1024 + (mt * 32 + l31) * 16 + 8 * hi) = pk;
      }
    }
    __syncthreads();                             // LP ready; LK(i) reads done
    // ---- PV: wave owns 32 d (wave*32), both m-tiles, K=64 ----
    #pragma unroll
    for (int kk = 0; kk < 4; kk++) {
      s8 bv = ld8(vtb + (long)(wave * 32 + l31) * N_ + n0 + kk * 16 + hi * 8);
      #pragma unroll
      for (int i = 0; i < 2; i++) {
        s8 ap = *reinterpret_cast<const s8*>(
            LP + (2 * kk + hi) * 1024 + (i * 32 + l31) * 16);
        acc[i] = mfma32(ap, bv, acc[i]);
      }
    }
  }
  // store partial tile [64m][128d] f32; C: col=d, row m=(reg&3)+8*(reg>>2)+4*hi
  float* pt = part + (long)bid * 64 * 128;
  #pragma unroll
  for (int i = 0; i < 2; i++)
    #pragma unroll
    for (int g = 0; g < 4; g++)
      #pragma unroll
      for (int r = 0; r < 4; r++)
        pt[(i * 32 + g * 8 + 4 * hi + r) * 128 + wave * 32 + l31] = acc[i][g * 4 + r];
}

// Pass 2b: out = sum_ns partial + vfeat  (f32 out)
__global__ __launch_bounds__(256) void attn_reduce(const float* __restrict__ part,
    const float* __restrict__ vfeat, float* __restrict__ out, int nsplit) {
  const int g4 = blockIdx.x * 256 + threadIdx.x;     // 0 .. B*M*D/4-1
  const int b = g4 >> 17;                            // M*D/4 = 131072
  const int rem = g4 & 131071;
  const int m = rem >> 5;
  const int d4 = rem & 31;
  const int mb = m >> 6, mr = m & 63;
  const long base = ((long)(b * 64 + mb) * nsplit) * 8192 + mr * 128 + d4 * 4;
  f4 s = *reinterpret_cast<const f4*>(vfeat + (long)g4 * 4);
  for (int ns = 0; ns < nsplit; ns++)
    s += *reinterpret_cast<const f4*>(part + base + ns * 8192);
  *reinterpret_cast<f4*>(out + (long)g4 * 4) = s;
}

extern "C" void kernel_launch(void* const* d_in, const int* in_sizes, int n_in,
                              void* d_out, int out_size, void* d_ws, size_t ws_size,
                              hipStream_t stream) {
  const float* p_xyz  = (const float*)d_in[0];
  const float* v_xyz  = (const float*)d_in[1];
  const float* p_feat = (const float*)d_in[2];
  const float* v_feat = (const float*)d_in[3];
  const float* aW1 = (const float*)d_in[4],  *ab1 = (const float*)d_in[5];
  const float* aW2 = (const float*)d_in[6],  *ab2 = (const float*)d_in[7];
  const float* bW1 = (const float*)d_in[8],  *bb1 = (const float*)d_in[9];
  const float* bW2 = (const float*)d_in[10], *bb2 = (const float*)d_in[11];
  const float* oW1 = (const float*)d_in[12], *ob1 = (const float*)d_in[13];
  const float* oW2 = (const float*)d_in[14], *ob2 = (const float*)d_in[15];
  const float* dW1 = (const float*)d_in[16], *db1 = (const float*)d_in[17];
  const float* dW2 = (const float*)d_in[18], *db2 = (const float*)d_in[19];

  char* ws = (char*)d_ws;
  u16* wt    = (u16*)ws;                               // 7 * 16384 bf16 elems
  u16* aW1t  = wt + 0 * 16384;
  u16* aW2t  = wt + 1 * 16384;
  u16* bW1t  = wt + 2 * 16384;
  u16* bW2t  = wt + 3 * 16384;
  u16* oW1t  = wt + 4 * 16384;
  u16* oW2t  = wt + 5 * 16384;
  u16* dW2t  = wt + 6 * 16384;
  u16* qbuf  = (u16*)(ws + 262144);                    // B*M*D bf16 = 2 MB
  u16* kpvb  = (u16*)(ws + 2359296);                   // B*N*D bf16 = 8 MB
  u16* vtb   = (u16*)(ws + 10747904);                  // Vt = 8 MB
  float* invb = (float*)(ws + 19136512);               // B*N f32 = 128 KB
  float* partb = (float*)(ws + 19267584);              // nsplit * 4 MB

  const size_t part_off = 19267584;
  int lgns = (ws_size >= part_off + (size_t)8 * B_ * M_ * D_ * 4) ? 3 : 2;
  const int nsplit = 1 << lgns;
  const int nslice = N_ / nsplit;

  wtrans<<<dim3(7), dim3(256), 0, stream>>>(aW1, aW2, bW1, bW2, oW1, oW2, dW2, wt);
  mlp2<0><<<dim3((B_ * M_) / 64), dim3(256), 0, stream>>>(v_feat, aW1t, ab1, aW2t, ab2, qbuf);
  mlp2<1><<<dim3((B_ * N_) / 64), dim3(256), 0, stream>>>(p_feat, oW1t, ob1, oW2t, ob2, vtb);
  kpv_kernel<<<dim3((B_ * N_) / 64), dim3(256), 0, stream>>>(
      p_feat, p_xyz, v_xyz, bW1t, bb1, bW2t, bb2, dW1, db1, dW2t, db2, kpvb);
  colsum_v2<<<dim3(B_ * (N_ / 128)), dim3(512), 0, stream>>>(qbuf, kpvb, invb);
  attn_v7<<<dim3(B_ * 64 * nsplit), dim3(256), 0, stream>>>(qbuf, kpvb, vtb, invb, partb,
                                                            lgns, nslice);
  attn_reduce<<<dim3((B_ * M_ * D_ / 4) / 256), dim3(256), 0, stream>>>(partb, v_feat,
                                                                        (float*)d_out,
                                                                        nsplit);
}